// Round 20
// baseline (371.255 us; speedup 1.0000x reference)
//
#include <hip/hip_runtime.h>
#include <math.h>

#define BB 8
#define NN 1024
#define HH 32
#define II 192   // K * C = 3*64
#define DD 16
#define BN (BB*NN)
#define MT 16    // row tile

typedef __attribute__((ext_vector_type(8))) short short8v;   // 8 bf16
typedef __attribute__((ext_vector_type(4))) float float4v;   // MFMA C/D

union Frag8 { short8v v; uint2 u[2]; };

// fp32 -> bf16 round-to-nearest-even (finite inputs)
static __device__ inline ushort bf(float x) {
  union { float f; unsigned u; } c; c.f = x;
  unsigned r = c.u + 0x7FFFu + ((c.u >> 16) & 1u);
  return (ushort)(r >> 16);
}

// ---------------------------------------------------------------------------
// prep_w body: W[d][i][o] f32 -> Wt[d][o][i] bf16 (one block per (layer,d))
// ---------------------------------------------------------------------------
template <int O>
static __device__ void prep_w_body(const float* __restrict__ W,
                                   ushort* __restrict__ Wt, int d,
                                   float* lds)  // stride O+1
{
  const float* Wd = W + (size_t)d * II * O;
  ushort* Wtd = Wt + (size_t)d * O * II;
  const int tid = threadIdx.x;
  for (int f = tid; f < II * O / 4; f += 256) {
    int i = f / (O / 4);
    int o4 = (f % (O / 4)) * 4;
    float4 v = *(const float4*)(Wd + (size_t)i * O + o4);
    lds[i * (O + 1) + o4 + 0] = v.x; lds[i * (O + 1) + o4 + 1] = v.y;
    lds[i * (O + 1) + o4 + 2] = v.z; lds[i * (O + 1) + o4 + 3] = v.w;
  }
  __syncthreads();
  for (int h = tid; h < II * O / 2; h += 256) {
    int o = h / (II / 2);
    int i2 = (h % (II / 2)) * 2;
    unsigned p = (unsigned)bf(lds[i2 * (O + 1) + o]) |
                 ((unsigned)bf(lds[(i2 + 1) * (O + 1) + o]) << 16);
    *(unsigned*)(Wtd + (size_t)o * II + i2) = p;
  }
}

// ---------------------------------------------------------------------------
// prep_all: [0,1024) S->bf16 | [1024,1056) w64 | [1056,1088) w32
//           [1088,1472) transposes: X[BN,32] f32 -> xbT rows [32][BN] bf16
// ---------------------------------------------------------------------------
__global__ __launch_bounds__(256) void prep_all(
    const float* __restrict__ S, ushort* __restrict__ Sb,
    const float* __restrict__ gw0, const float* __restrict__ gw1,
    ushort* __restrict__ wtg0, ushort* __restrict__ wtg1,
    const float* __restrict__ uw0, const float* __restrict__ uw1,
    ushort* __restrict__ wtu0, ushort* __restrict__ wtu1,
    const float* __restrict__ xt, const float* __restrict__ st0,
    const float* __restrict__ st1,
    ushort* __restrict__ xbTg0, ushort* __restrict__ xbTu0,
    ushort* __restrict__ xbTg1)
{
  __shared__ float ldsf[II * 65];   // 49.9 KB; reused by all branches
  int bx = blockIdx.x;
  const int tid = threadIdx.x;

  if (bx < 1024) {               // ---- S convert
    int idx = bx * 256 + tid;
    float4 v = ((const float4*)S)[idx];
    ushort4 o; o.x = bf(v.x); o.y = bf(v.y); o.z = bf(v.z); o.w = bf(v.w);
    ((ushort4*)Sb)[idx] = o;
    return;
  }
  bx -= 1024;
  if (bx < 32) {                 // ---- gate weights
    prep_w_body<64>(bx >= 16 ? gw1 : gw0, bx >= 16 ? wtg1 : wtg0, bx & 15, ldsf);
    return;
  }
  bx -= 32;
  if (bx < 32) {                 // ---- upd weights
    prep_w_body<32>(bx >= 16 ? uw1 : uw0, bx >= 16 ? wtu1 : wtu0, bx & 15, ldsf);
    return;
  }
  bx -= 32;
  // ---- transposes
  const int tensor = bx >> 7, seg = bx & 127;
  const float* src = tensor == 0 ? xt : (tensor == 1 ? st0 : st1);
  ushort* T = (ushort*)ldsf;     // [32][72]
  const int n0 = seg * 64;
#pragma unroll
  for (int q = 0; q < 2; ++q) {
    int f = tid + q * 256;
    int n = f >> 3, c4 = (f & 7) * 4;
    float4 v = *(const float4*)(src + (size_t)(n0 + n) * 32 + c4);
    T[(c4 + 0) * 72 + n] = bf(v.x); T[(c4 + 1) * 72 + n] = bf(v.y);
    T[(c4 + 2) * 72 + n] = bf(v.z); T[(c4 + 3) * 72 + n] = bf(v.w);
  }
  __syncthreads();
#pragma unroll
  for (int q = 0; q < 2; ++q) {
    int f = tid + q * 256;
    int c = f >> 4, p = f & 15;
    uint2 val = *(const uint2*)&T[c * 72 + p * 4];
    size_t off = (size_t)c * BN + n0 + p * 4;
    if (tensor == 0) {
      *(uint2*)&xbTg0[off] = val;
      *(uint2*)&xbTu0[off] = val;
    } else if (tensor == 1) {
      *(uint2*)&xbTg0[(size_t)32 * BN + off] = val;
    } else {
      *(uint2*)&xbTg1[(size_t)32 * BN + off] = val;
    }
  }
}

// ---------------------------------------------------------------------------
// S2b = bf16( 2 * Sb @ Sb )   [1024][1024], 32x32 tiles, grid (32,32)
// ---------------------------------------------------------------------------
__global__ __launch_bounds__(256) void prep_s2(
    const ushort* __restrict__ Sb, ushort* __restrict__ S2b)
{
  __shared__ ushort A[32][136];
  __shared__ ushort Bt[32][132];
  const int m0 = blockIdx.x * 32, n0 = blockIdx.y * 32;
  const int tid = threadIdx.x;
  const int w = tid >> 6, l = tid & 63;
  const int l15 = l & 15, l4 = l >> 4;
  const int wr = (w & 1) * 16, wc = (w >> 1) * 16;

  float4v acc = (float4v){0.f, 0.f, 0.f, 0.f};
  for (int k0 = 0; k0 < NN; k0 += 128) {
    __syncthreads();
#pragma unroll
    for (int q = 0; q < 2; ++q) {
      int f = tid + q * 256;
      int row = f >> 4, s8 = (f & 15) * 8;
      *(uint4*)&A[row][s8] = *(const uint4*)(Sb + (size_t)(m0 + row) * NN + k0 + s8);
    }
#pragma unroll
    for (int q = 0; q < 2; ++q) {
      int u = tid + q * 256;
      int kp = u >> 3, c4 = (u & 7) * 4;
      ushort4 a = *(const ushort4*)(Sb + (size_t)(k0 + 2 * kp) * NN + n0 + c4);
      ushort4 b = *(const ushort4*)(Sb + (size_t)(k0 + 2 * kp + 1) * NN + n0 + c4);
      *(unsigned*)&Bt[c4 + 0][2 * kp] = (unsigned)a.x | ((unsigned)b.x << 16);
      *(unsigned*)&Bt[c4 + 1][2 * kp] = (unsigned)a.y | ((unsigned)b.y << 16);
      *(unsigned*)&Bt[c4 + 2][2 * kp] = (unsigned)a.z | ((unsigned)b.z << 16);
      *(unsigned*)&Bt[c4 + 3][2 * kp] = (unsigned)a.w | ((unsigned)b.w << 16);
    }
    __syncthreads();
#pragma unroll
    for (int ks = 0; ks < 4; ++ks) {
      int kb = ks * 32 + l4 * 4;
      Frag8 af, bfr;
      af.u[0] = *(const uint2*)&A[wr + l15][kb];
      af.u[1] = *(const uint2*)&A[wr + l15][kb + 16];
      bfr.u[0] = *(const uint2*)&Bt[wc + l15][kb];
      bfr.u[1] = *(const uint2*)&Bt[wc + l15][kb + 16];
      acc = __builtin_amdgcn_mfma_f32_16x16x32_bf16(af.v, bfr.v, acc, 0, 0, 0);
    }
  }
#pragma unroll
  for (int r = 0; r < 4; ++r)
    S2b[(size_t)(m0 + wr + l4 * 4 + r) * NN + n0 + wc + l15] = bf(2.f * acc[r]);
}

// ---------------------------------------------------------------------------
// Fused graph-conv, BARRIER-FREE operand streaming: all MFMA operands read
// per-lane directly from global (L2-resident Sb/S2b/xbT/Wt). LDS only for the
// cross-wave A=[X,T1,T2] exchange (single barrier). M-tile 16, grid 512.
// ---------------------------------------------------------------------------
template <int PHASE>
__global__ __launch_bounds__(256) void gconv_fused(
    const float* __restrict__ xb1,    // [BN,32] f32 (cur)
    const float* __restrict__ xb2,    // [BN,32] f32 (gate: state; upd: zs)
    const ushort* __restrict__ xbT,   // [64][BN] bf16 X^T
    const ushort* __restrict__ Sb,    // [1024][1024] bf16
    const ushort* __restrict__ S2b,   // [1024][1024] bf16 (=2S^2)
    const float* __restrict__ emb,    // [BN,16]
    const ushort* __restrict__ Wt,    // [16][O][192] bf16
    const float* __restrict__ bias,   // [16][O]
    ushort* __restrict__ gT1c,        // [BN,32] bf16: cur-half T1
    float* __restrict__ gT2c,         // [BN,32] f32 : cur-half raw T2
    float* __restrict__ zr,           // PHASE0: out [BN,64]; PHASE1: in
    float* __restrict__ zs,           // PHASE0: out [BN,32]
    ushort* __restrict__ zsT,         // PHASE0: out [32][BN] bf16
    const float* __restrict__ state,  // PHASE1: [BN,32]
    float* __restrict__ hid,          // PHASE1: out [BN,32]
    float* __restrict__ outp,         // PHASE1: dup out (may be null)
    ushort* __restrict__ nxbTg)       // PHASE1 l=0: next-layer curT (gate buf)
{
  constexpr int O = PHASE == 0 ? 64 : 32;
  __shared__ ushort A_sm[MT][200];    // [X | T1 | T2] bf16
  __shared__ float emb_sm[MT][17];
  __shared__ float bias_sm[16][64];

  const int b = blockIdx.y;
  const int m0 = blockIdx.x * MT;
  const int tid = threadIdx.x;
  const int w = tid >> 6, l = tid & 63;
  const int l15 = l & 15, l4 = l >> 4;
  const int wcp = (PHASE == 0) ? w * 16 : (w & 1) * 16;

  // ---- stage emb/bias early (no dependency)
  if (tid < MT * 4) {
    int row = tid >> 2, d4 = (tid & 3) * 4;
    float4 v = *(const float4*)(emb + ((size_t)b * NN + m0 + row) * DD + d4);
    emb_sm[row][d4 + 0] = v.x; emb_sm[row][d4 + 1] = v.y;
    emb_sm[row][d4 + 2] = v.z; emb_sm[row][d4 + 3] = v.w;
  }
  for (int f = tid; f < DD * O / 4; f += 256) {
    int d = f / (O / 4), o4 = (f % (O / 4)) * 4;
    *(float4*)&bias_sm[d][o4] = *(const float4*)(bias + (size_t)d * O + o4);
  }
  {  // X cols of A_sm: 16 rows x 64 cols = 256 float4 -> 1 per thread
    int row = tid >> 4, c4 = (tid & 15) * 4;
    const float* src = (c4 < 32) ? xb1 : xb2;
    float4 v = *(const float4*)(src + ((size_t)b * NN + m0 + row) * 32 + (c4 & 31));
    ushort4 o; o.x = bf(v.x); o.y = bf(v.y); o.z = bf(v.z); o.w = bf(v.w);
    *(ushort4*)&A_sm[row][c4] = o;
  }

  // ================= phase A: propagation, barrier-free =================
  // Lane operand rows (direct global): A1/A2 row = m0+l15; B row = X^T col.
  float4v acc1 = (float4v){0.f, 0.f, 0.f, 0.f};
  float4v acc2 = (float4v){0.f, 0.f, 0.f, 0.f};
  {
    const ushort* a1p = Sb + (size_t)(m0 + l15) * NN;
    const ushort* a2p = S2b + (size_t)(m0 + l15) * NN;
    const ushort* bp = xbT + (size_t)((PHASE == 1 ? 32 : 0) + wcp + l15) * BN +
                       (size_t)b * NN;
#pragma unroll 8
    for (int ks = 0; ks < NN / 32; ++ks) {
      int kb = ks * 32 + l4 * 4;
      Frag8 a1, a2, b0;
      a1.u[0] = *(const uint2*)(a1p + kb);
      a1.u[1] = *(const uint2*)(a1p + kb + 16);
      a2.u[0] = *(const uint2*)(a2p + kb);
      a2.u[1] = *(const uint2*)(a2p + kb + 16);
      b0.u[0] = *(const uint2*)(bp + kb);
      b0.u[1] = *(const uint2*)(bp + kb + 16);
      acc1 = __builtin_amdgcn_mfma_f32_16x16x32_bf16(a1.v, b0.v, acc1, 0, 0, 0);
      acc2 = __builtin_amdgcn_mfma_f32_16x16x32_bf16(a2.v, b0.v, acc2, 0, 0, 0);
    }
  }

  // ---- gate: store cur-half T1/T2 for the upd kernel (waves 0,1)
  if (PHASE == 0 && w < 2) {
#pragma unroll
    for (int r = 0; r < 4; ++r) {
      size_t m = (size_t)b * NN + m0 + l4 * 4 + r;
      gT1c[m * 32 + wcp + l15] = bf(acc1[r]);
      gT2c[m * 32 + wcp + l15] = acc2[r];
    }
  }

  // ---- finish A_sm: T1/T2 columns
  if (PHASE == 1) {   // cur-half from the gate's stores (bit-identical)
#pragma unroll
    for (int q = 0; q < 2; ++q) {
      int e = tid + q * 256;
      int row = e >> 5, c = e & 31;
      size_t m = (size_t)b * NN + m0 + row;
      A_sm[row][64 + c] = gT1c[m * 32 + c];
      A_sm[row][128 + c] = bf(gT2c[m * 32 + c] - xb1[m * 32 + c]);
    }
  }
  {  // locally-computed T1/T2: gate cols 0..63; upd zs cols 32..63
    const int colX = (PHASE == 0 ? 0 : 32) + wcp + l15;
    if (PHASE == 0 || w < 2) {
#pragma unroll
      for (int r = 0; r < 4; ++r) {
        int row = l4 * 4 + r;
        const float* src = (colX < 32) ? xb1 : xb2;
        float xv = src[((size_t)b * NN + m0 + row) * 32 + (colX & 31)];
        A_sm[row][64 + colX] = bf(acc1[r]);
        A_sm[row][128 + colX] = bf(acc2[r] - xv);
      }
    }
  }
  __syncthreads();   // the ONLY barrier: A_sm published for all waves

  // ================= phase B: contraction, barrier-free W streaming ========
  const int ocol = (PHASE == 0 ? w * 16 : (w & 1) * 16) + l15;
  const int erow = l4 * 4;
  const ushort* wp = Wt + (size_t)ocol * II;   // + d*O*II + kb

  float4v outacc = (float4v){0.f, 0.f, 0.f, 0.f};

#pragma unroll 4
  for (int d = 0; d < DD; ++d) {
    const ushort* wpd = wp + (size_t)d * O * II;
    float4v acc = (float4v){0.f, 0.f, 0.f, 0.f};
#pragma unroll
    for (int ks = 0; ks < 6; ++ks) {
      int kb = ks * 32 + l4 * 4;
      Frag8 af, bfr;
      af.u[0] = *(const uint2*)&A_sm[l15][kb];
      af.u[1] = *(const uint2*)&A_sm[l15][kb + 16];
      bfr.u[0] = *(const uint2*)(wpd + kb);
      bfr.u[1] = *(const uint2*)(wpd + kb + 16);
      acc = __builtin_amdgcn_mfma_f32_16x16x32_bf16(af.v, bfr.v, acc, 0, 0, 0);
    }
    float bb = bias_sm[d][ocol];
    outacc[0] += emb_sm[erow + 0][d] * (acc[0] + bb);
    outacc[1] += emb_sm[erow + 1][d] * (acc[1] + bb);
    outacc[2] += emb_sm[erow + 2][d] * (acc[2] + bb);
    outacc[3] += emb_sm[erow + 3][d] * (acc[3] + bb);
  }

  // ================= fused epilogue =================
  if (PHASE == 0) {
    float zss[4];
#pragma unroll
    for (int r = 0; r < 4; ++r) {
      size_t m = (size_t)b * NN + m0 + erow + r;
      float zv = 1.f / (1.f + __expf(-outacc[r]));
      zr[m * 64 + ocol] = zv;
      if (ocol < 32) {
        float sv = zv * xb2[m * 32 + ocol];
        zs[m * 32 + ocol] = sv;
        zss[r] = sv;
      }
    }
    if (ocol < 32) {
      ushort4 pk; pk.x = bf(zss[0]); pk.y = bf(zss[1]);
      pk.z = bf(zss[2]); pk.w = bf(zss[3]);
      *(ushort4*)&zsT[(size_t)ocol * BN + (size_t)b * NN + m0 + erow] = pk;
    }
  } else if (w < 2) {
    float res[4];
#pragma unroll
    for (int r = 0; r < 4; ++r) {
      size_t m = (size_t)b * NN + m0 + erow + r;
      float hc = tanhf(outacc[r]);
      float rg = zr[m * 64 + 32 + ocol];
      float st = state[m * 32 + ocol];
      res[r] = rg * st + (1.f - rg) * hc;
      hid[m * 32 + ocol] = res[r];
      if (outp) outp[m * 32 + ocol] = res[r];
    }
    if (nxbTg) {       // next layer's curT (gate buffer rows 0..31)
      ushort4 pk; pk.x = bf(res[0]); pk.y = bf(res[1]);
      pk.z = bf(res[2]); pk.w = bf(res[3]);
      *(ushort4*)&nxbTg[(size_t)ocol * BN + (size_t)b * NN + m0 + erow] = pk;
    }
  }
}

// ---------------------------------------------------------------------------
extern "C" void kernel_launch(void* const* d_in, const int* in_sizes, int n_in,
                              void* d_out, int out_size, void* d_ws, size_t ws_size,
                              hipStream_t stream)
{
  const float* xt         = (const float*)d_in[0];
  const float* init_state = (const float*)d_in[1];
  const float* S          = (const float*)d_in[2];
  const float* emb        = (const float*)d_in[3];

  float* out    = (float*)d_out;          // [BN,32] final cur
  float* hidden = out + (size_t)BN * HH;  // [2, BN, 32]

  float* zr = (float*)d_ws;                        // [BN,64]  2.0 MB
  float* zs = zr + (size_t)BN * 64;                // [BN,32]  1.0 MB
  ushort* wtg0 = (ushort*)(zs + (size_t)BN * 32);  // bf16 weights 1.5 MB
  ushort* wtu0 = wtg0 + (size_t)DD * II * 64;
  ushort* wtg1 = wtu0 + (size_t)DD * II * 32;
  ushort* wtu1 = wtg1 + (size_t)DD * II * 64;
  ushort* Sb   = wtu1 + (size_t)DD * II * 32;      // [1024][1024] bf16 2 MB
  ushort* S2b  = Sb + (size_t)NN * NN;             // [1024][1024] bf16 2 MB
  ushort* xbTg0 = S2b + (size_t)NN * NN;           // 4 x [64][BN] bf16 4 MB
  ushort* xbTu0 = xbTg0 + (size_t)64 * BN;
  ushort* xbTg1 = xbTu0 + (size_t)64 * BN;
  ushort* xbTu1 = xbTg1 + (size_t)64 * BN;
  ushort* gT1c = xbTu1 + (size_t)64 * BN;          // [BN,32] bf16 0.5 MB
  float*  gT2c = (float*)(gT1c + (size_t)32 * BN); // [BN,32] f32  1.0 MB

  const float* st0 = init_state;
  const float* st1 = init_state + (size_t)BN * HH;
  float* hid0 = hidden;
  float* hid1 = hidden + (size_t)BN * HH;

  prep_all<<<1472, 256, 0, stream>>>(
      S, Sb,
      (const float*)d_in[4], (const float*)d_in[8], wtg0, wtg1,
      (const float*)d_in[6], (const float*)d_in[10], wtu0, wtu1,
      xt, st0, st1, xbTg0, xbTu0, xbTg1);
  prep_s2<<<dim3(NN / 32, NN / 32), 256, 0, stream>>>(Sb, S2b);

  dim3 g(NN / MT, BB);   // 64 x 8 = 512 blocks (2/CU)
  // ---- layer 0
  gconv_fused<0><<<g, 256, 0, stream>>>(
      xt, st0, xbTg0, Sb, S2b, emb, wtg0, (const float*)d_in[5],
      gT1c, gT2c, zr, zs, xbTu0 + (size_t)32 * BN, nullptr, nullptr, nullptr,
      nullptr);
  gconv_fused<1><<<g, 256, 0, stream>>>(
      xt, zs, xbTu0, Sb, S2b, emb, wtu0, (const float*)d_in[7],
      gT1c, gT2c, zr, nullptr, nullptr, st0, hid0, nullptr, xbTg1);
  // ---- layer 1
  gconv_fused<0><<<g, 256, 0, stream>>>(
      hid0, st1, xbTg1, Sb, S2b, emb, wtg1, (const float*)d_in[9],
      gT1c, gT2c, zr, zs, xbTu1 + (size_t)32 * BN, nullptr, nullptr, nullptr,
      nullptr);
  gconv_fused<1><<<g, 256, 0, stream>>>(
      hid0, zs, xbTu1, Sb, S2b, emb, wtu1, (const float*)d_in[11],
      gT1c, gT2c, zr, nullptr, nullptr, st1, hid1, out, nullptr);
}

// Round 23
// 100.323 us; speedup vs baseline: 3.7006x; 3.7006x over previous
//
#include <hip/hip_runtime.h>
#include <math.h>

#define BB 8
#define NN 1024
#define HH 32
#define II 192   // K * C = 3*64
#define DD 16
#define BN (BB*NN)
#define MT 16    // row tile
#define FR 512   // ushorts per (ks) fragment slab = 64 lanes * 8

typedef __attribute__((ext_vector_type(8))) short short8v;   // 8 bf16
typedef __attribute__((ext_vector_type(4))) float float4v;   // MFMA C/D

union Frag8 { short8v v; uint2 u[2]; uint4 q; };

// fp32 -> bf16 round-to-nearest-even (finite inputs)
static __device__ inline ushort bf(float x) {
  union { float f; unsigned u; } c; c.f = x;
  unsigned r = c.u + 0x7FFFu + ((c.u >> 16) & 1u);
  return (ushort)(r >> 16);
}

static __device__ inline uint4 pack8(const ushort e[8]) {
  uint4 v;
  v.x = (unsigned)e[0] | ((unsigned)e[1] << 16);
  v.y = (unsigned)e[2] | ((unsigned)e[3] << 16);
  v.z = (unsigned)e[4] | ((unsigned)e[5] << 16);
  v.w = (unsigned)e[6] | ((unsigned)e[7] << 16);
  return v;
}

// ---------------------------------------------------------------------------
// W[d][i][o] f32 -> fragment order WF[d][cg][ks][lane][8]
// ---------------------------------------------------------------------------
template <int O>
static __device__ void prep_w_frag(const float* __restrict__ W,
                                   ushort* __restrict__ WF, int d,
                                   float* lds)  // stride O+1
{
  constexpr int NCG = O / 16;
  const float* Wd = W + (size_t)d * II * O;
  ushort* WFd = WF + (size_t)d * NCG * 6 * FR;
  const int tid = threadIdx.x;
  for (int f = tid; f < II * O / 4; f += 256) {
    int i = f / (O / 4);
    int o4 = (f % (O / 4)) * 4;
    float4 v = *(const float4*)(Wd + (size_t)i * O + o4);
    lds[i * (O + 1) + o4 + 0] = v.x; lds[i * (O + 1) + o4 + 1] = v.y;
    lds[i * (O + 1) + o4 + 2] = v.z; lds[i * (O + 1) + o4 + 3] = v.w;
  }
  __syncthreads();
  for (int f = tid; f < NCG * 6 * 64; f += 256) {
    int rem = f % 384;
    int ks = rem >> 6, l = rem & 63;
    int o = (f / 384) * 16 + (l & 15);
    int kb = ks * 32 + (l >> 4) * 4;
    ushort e[8];
#pragma unroll
    for (int j = 0; j < 4; ++j) {
      e[j] = bf(lds[(kb + j) * (O + 1) + o]);
      e[4 + j] = bf(lds[(kb + 16 + j) * (O + 1) + o]);
    }
    *(uint4*)(WFd + (size_t)f * 8) = pack8(e);
  }
}

// ---------------------------------------------------------------------------
// prep_all: [0,1024) S->Sb row-major | [1024,1056) gate W frag |
//           [1056,1088) upd W frag | [1088,1472) X transposes -> xbTF frags |
//           [1472,1536) SbF fragments (from f32 S directly)
// ---------------------------------------------------------------------------
__global__ __launch_bounds__(256) void prep_all(
    const float* __restrict__ S, ushort* __restrict__ Sb,
    ushort* __restrict__ SbF,
    const float* __restrict__ gw0, const float* __restrict__ gw1,
    ushort* __restrict__ wfg0, ushort* __restrict__ wfg1,
    const float* __restrict__ uw0, const float* __restrict__ uw1,
    ushort* __restrict__ wfu0, ushort* __restrict__ wfu1,
    const float* __restrict__ xt, const float* __restrict__ st0,
    const float* __restrict__ st1,
    ushort* __restrict__ xbTFg0, ushort* __restrict__ xbTFg1)
{
  __shared__ float ldsf[II * 65];   // 49.9 KB; reused by all branches
  int bx = blockIdx.x;
  const int tid = threadIdx.x;

  if (bx < 1024) {               // ---- S convert (row-major, for prep_s2)
    int idx = bx * 256 + tid;
    float4 v = ((const float4*)S)[idx];
    ushort4 o; o.x = bf(v.x); o.y = bf(v.y); o.z = bf(v.z); o.w = bf(v.w);
    ((ushort4*)Sb)[idx] = o;
    return;
  }
  bx -= 1024;
  if (bx < 32) {                 // ---- gate weights -> fragments
    prep_w_frag<64>(bx >= 16 ? gw1 : gw0, bx >= 16 ? wfg1 : wfg0, bx & 15, ldsf);
    return;
  }
  bx -= 32;
  if (bx < 32) {                 // ---- upd weights -> fragments
    prep_w_frag<32>(bx >= 16 ? uw1 : uw0, bx >= 16 ? wfu1 : wfu0, bx & 15, ldsf);
    return;
  }
  bx -= 32;
  if (bx < 384) {                // ---- X transposes -> xbTF fragments
    const int tensor = bx / 128, seg = bx % 128;
    const float* src = tensor == 0 ? xt : (tensor == 1 ? st0 : st1);
    ushort* T = (ushort*)ldsf;   // [32][72]
    const int n0 = seg * 64;     // global node base (within BN)
#pragma unroll
    for (int q = 0; q < 2; ++q) {
      int f = tid + q * 256;
      int n = f >> 3, c4 = (f & 7) * 4;
      float4 v = *(const float4*)(src + (size_t)(n0 + n) * 32 + c4);
      T[(c4 + 0) * 72 + n] = bf(v.x); T[(c4 + 1) * 72 + n] = bf(v.y);
      T[(c4 + 2) * 72 + n] = bf(v.z); T[(c4 + 3) * 72 + n] = bf(v.w);
    }
    __syncthreads();
    {
      int gg = tid >> 7, ksl = (tid >> 6) & 1, l = tid & 63;
      int c = gg * 16 + (l & 15);
      int nb = ksl * 32 + (l >> 4) * 4;
      ushort e[8];
#pragma unroll
      for (int j = 0; j < 4; ++j) {
        e[j] = T[c * 72 + nb + j];
        e[4 + j] = T[c * 72 + nb + 16 + j];
      }
      int b = seg >> 4;                       // batch
      int ks = (seg & 15) * 2 + ksl;          // ks within batch (0..31)
      ushort* dst; int g;
      if (tensor == 0)      { dst = xbTFg0; g = gg; }      // xt -> g0 grp 0,1
      else if (tensor == 1) { dst = xbTFg0; g = 2 + gg; }  // st0 -> g0 grp 2,3
      else                  { dst = xbTFg1; g = 2 + gg; }  // st1 -> g1 grp 2,3
      *(uint4*)(dst + (((size_t)b * 4 + g) * 32 + ks) * FR + (size_t)l * 8) =
          pack8(e);
    }
    return;
  }
  bx -= 384;
  {                              // ---- SbF fragments: mt = bx (0..63)
    const int mt = bx;
#pragma unroll
    for (int q = 0; q < 8; ++q) {
      int f = tid + q * 256;     // over 32 ks * 64 lanes
      int ks = f >> 6, l = f & 63;
      int row = mt * 16 + (l & 15);
      int kb = ks * 32 + (l >> 4) * 4;
      float4 lo = *(const float4*)(S + (size_t)row * NN + kb);
      float4 hi = *(const float4*)(S + (size_t)row * NN + kb + 16);
      ushort e[8] = {bf(lo.x), bf(lo.y), bf(lo.z), bf(lo.w),
                     bf(hi.x), bf(hi.y), bf(hi.z), bf(hi.w)};
      *(uint4*)(SbF + ((size_t)mt * 32 + ks) * FR + (size_t)l * 8) = pack8(e);
    }
  }
}

// ---------------------------------------------------------------------------
// S2bF = fragments of bf16( 2 * Sb @ Sb ). grid (32, 32): rows m0=bx*32,
// cols n0=by*32 (one ks block). C tile -> LDS transpose -> fragment write.
// ---------------------------------------------------------------------------
__global__ __launch_bounds__(256) void prep_s2(
    const ushort* __restrict__ Sb, ushort* __restrict__ S2bF)
{
  __shared__ ushort A[32][136];
  __shared__ ushort Bt[32][132];
  __shared__ ushort C2[32][36];
  const int m0 = blockIdx.x * 32, n0 = blockIdx.y * 32;
  const int tid = threadIdx.x;
  const int w = tid >> 6, l = tid & 63;
  const int l15 = l & 15, l4 = l >> 4;
  const int wr = (w & 1) * 16, wc = (w >> 1) * 16;

  float4v acc = (float4v){0.f, 0.f, 0.f, 0.f};
  for (int k0 = 0; k0 < NN; k0 += 128) {
    __syncthreads();
#pragma unroll
    for (int q = 0; q < 2; ++q) {
      int f = tid + q * 256;
      int row = f >> 4, s8 = (f & 15) * 8;
      *(uint4*)&A[row][s8] = *(const uint4*)(Sb + (size_t)(m0 + row) * NN + k0 + s8);
    }
#pragma unroll
    for (int q = 0; q < 2; ++q) {
      int u = tid + q * 256;
      int kp = u >> 3, c4 = (u & 7) * 4;
      ushort4 a = *(const ushort4*)(Sb + (size_t)(k0 + 2 * kp) * NN + n0 + c4);
      ushort4 b = *(const ushort4*)(Sb + (size_t)(k0 + 2 * kp + 1) * NN + n0 + c4);
      *(unsigned*)&Bt[c4 + 0][2 * kp] = (unsigned)a.x | ((unsigned)b.x << 16);
      *(unsigned*)&Bt[c4 + 1][2 * kp] = (unsigned)a.y | ((unsigned)b.y << 16);
      *(unsigned*)&Bt[c4 + 2][2 * kp] = (unsigned)a.z | ((unsigned)b.z << 16);
      *(unsigned*)&Bt[c4 + 3][2 * kp] = (unsigned)a.w | ((unsigned)b.w << 16);
    }
    __syncthreads();
#pragma unroll
    for (int ks = 0; ks < 4; ++ks) {
      int kb = ks * 32 + l4 * 4;
      Frag8 af, bfr;
      af.u[0] = *(const uint2*)&A[wr + l15][kb];
      af.u[1] = *(const uint2*)&A[wr + l15][kb + 16];
      bfr.u[0] = *(const uint2*)&Bt[wc + l15][kb];
      bfr.u[1] = *(const uint2*)&Bt[wc + l15][kb + 16];
      acc = __builtin_amdgcn_mfma_f32_16x16x32_bf16(af.v, bfr.v, acc, 0, 0, 0);
    }
  }
  __syncthreads();
#pragma unroll
  for (int r = 0; r < 4; ++r)
    C2[wr + l4 * 4 + r][wc + l15] = bf(2.f * acc[r]);
  __syncthreads();
  if (tid < 128) {
    int fh = tid >> 6, l2 = tid & 63;
    ushort e[8];
#pragma unroll
    for (int j = 0; j < 4; ++j) {
      e[j] = C2[fh * 16 + (l2 & 15)][(l2 >> 4) * 4 + j];
      e[4 + j] = C2[fh * 16 + (l2 & 15)][(l2 >> 4) * 4 + 16 + j];
    }
    *(uint4*)(S2bF + ((size_t)(blockIdx.x * 2 + fh) * 32 + blockIdx.y) * FR +
              (size_t)l2 * 8) = pack8(e);
  }
}

// ---------------------------------------------------------------------------
// Fused graph-conv: barrier-free fragment streaming (coalesced uint4/lane).
// LDS only for A=[X,T1,T2] exchange (one barrier). M-tile 16, grid 512.
// ---------------------------------------------------------------------------
template <int PHASE>
__global__ __launch_bounds__(256) void gconv_fused(
    const float* __restrict__ xb1,    // [BN,32] f32 (cur)
    const float* __restrict__ xb2,    // [BN,32] f32 (gate: state; upd: zs)
    const ushort* __restrict__ xbTF,  // X^T fragments (gate 4 grp; upd 2 grp)
    const ushort* __restrict__ SbF,   // S fragments
    const ushort* __restrict__ S2bF,  // 2S^2 fragments
    const float* __restrict__ emb,    // [BN,16]
    const ushort* __restrict__ WF,    // W fragments [d][cg][ks][lane][8]
    const float* __restrict__ bias,   // [16][O]
    ushort* __restrict__ gT1c,        // [BN,32] bf16: cur-half T1
    float* __restrict__ gT2c,         // [BN,32] f32 : cur-half raw T2
    float* __restrict__ zr,           // PHASE0: out [BN,64]; PHASE1: in
    float* __restrict__ zs,           // PHASE0: out [BN,32] f32
    const float* __restrict__ state,  // PHASE1: [BN,32]
    float* __restrict__ hid,          // PHASE1: out [BN,32]
    float* __restrict__ outp,         // PHASE1: dup out (may be null)
    ushort* __restrict__ xbTFout)     // PHASE0: upd frags; PHASE1: next gate
{
  constexpr int O = PHASE == 0 ? 64 : 32;
  constexpr int NCG = O / 16;         // = groups per batch in xbTF buffer
  __shared__ ushort A_sm[MT][200];    // [X | T1 | T2] bf16
  __shared__ float emb_sm[MT][17];
  __shared__ float bias_sm[16][64];

  const int b = blockIdx.y;
  const int m0 = blockIdx.x * MT;
  const int tid = threadIdx.x;
  const int w = tid >> 6, l = tid & 63;
  const int l15 = l & 15, l4 = l >> 4;
  const int wcp = (PHASE == 0) ? w * 16 : (w & 1) * 16;

  // ---- stage emb/bias/A_sm-X early
  if (tid < MT * 4) {
    int row = tid >> 2, d4 = (tid & 3) * 4;
    float4 v = *(const float4*)(emb + ((size_t)b * NN + m0 + row) * DD + d4);
    emb_sm[row][d4 + 0] = v.x; emb_sm[row][d4 + 1] = v.y;
    emb_sm[row][d4 + 2] = v.z; emb_sm[row][d4 + 3] = v.w;
  }
  for (int f = tid; f < DD * O / 4; f += 256) {
    int d = f / (O / 4), o4 = (f % (O / 4)) * 4;
    *(float4*)&bias_sm[d][o4] = *(const float4*)(bias + (size_t)d * O + o4);
  }
  {
    int row = tid >> 4, c4 = (tid & 15) * 4;
    const float* src = (c4 < 32) ? xb1 : xb2;
    float4 v = *(const float4*)(src + ((size_t)b * NN + m0 + row) * 32 + (c4 & 31));
    ushort4 o; o.x = bf(v.x); o.y = bf(v.y); o.z = bf(v.z); o.w = bf(v.w);
    *(ushort4*)&A_sm[row][c4] = o;
  }

  // ================= phase A: propagation (fragment streams) ==============
  float4v acc1 = (float4v){0.f, 0.f, 0.f, 0.f};
  float4v acc2 = (float4v){0.f, 0.f, 0.f, 0.f};
  {
    const ushort* a1p = SbF + (size_t)blockIdx.x * 32 * FR + (size_t)l * 8;
    const ushort* a2p = S2bF + (size_t)blockIdx.x * 32 * FR + (size_t)l * 8;
    // FIX (R21 bug): batch stride is NCG groups (gate 4, upd 2), not 8.
    const ushort* bp = xbTF +
        (((size_t)b * NCG + (PHASE == 0 ? w : (w & 1))) * 32) * FR +
        (size_t)l * 8;
#pragma unroll 4
    for (int ks = 0; ks < 32; ++ks) {
      Frag8 a1, a2, b0;
      a1.q = *(const uint4*)(a1p + (size_t)ks * FR);
      a2.q = *(const uint4*)(a2p + (size_t)ks * FR);
      b0.q = *(const uint4*)(bp + (size_t)ks * FR);
      acc1 = __builtin_amdgcn_mfma_f32_16x16x32_bf16(a1.v, b0.v, acc1, 0, 0, 0);
      acc2 = __builtin_amdgcn_mfma_f32_16x16x32_bf16(a2.v, b0.v, acc2, 0, 0, 0);
    }
  }

  // ---- gate: store cur-half T1/T2 for the upd kernel (waves 0,1)
  if (PHASE == 0 && w < 2) {
#pragma unroll
    for (int r = 0; r < 4; ++r) {
      size_t m = (size_t)b * NN + m0 + l4 * 4 + r;
      gT1c[m * 32 + wcp + l15] = bf(acc1[r]);
      gT2c[m * 32 + wcp + l15] = acc2[r];
    }
  }

  // ---- finish A_sm: T1/T2 columns
  if (PHASE == 1) {   // cur-half from the gate's stores (bit-identical)
#pragma unroll
    for (int q = 0; q < 2; ++q) {
      int e = tid + q * 256;
      int row = e >> 5, c = e & 31;
      size_t m = (size_t)b * NN + m0 + row;
      A_sm[row][64 + c] = gT1c[m * 32 + c];
      A_sm[row][128 + c] = bf(gT2c[m * 32 + c] - xb1[m * 32 + c]);
    }
  }
  {
    const int colX = (PHASE == 0 ? 0 : 32) + wcp + l15;
    if (PHASE == 0 || w < 2) {
#pragma unroll
      for (int r = 0; r < 4; ++r) {
        int row = l4 * 4 + r;
        const float* src = (colX < 32) ? xb1 : xb2;
        float xv = src[((size_t)b * NN + m0 + row) * 32 + (colX & 31)];
        A_sm[row][64 + colX] = bf(acc1[r]);
        A_sm[row][128 + colX] = bf(acc2[r] - xv);
      }
    }
  }
  __syncthreads();   // the ONLY barrier

  // ================= phase B: contraction (W fragment streams) ============
  const int cg = (PHASE == 0) ? w : (w & 1);
  const int ocol = cg * 16 + l15;
  const int erow = l4 * 4;
  const ushort* wfp = WF + (size_t)cg * 6 * FR + (size_t)l * 8;

  float4v outacc = (float4v){0.f, 0.f, 0.f, 0.f};

#pragma unroll 2
  for (int d = 0; d < DD; ++d) {
    const ushort* wpd = wfp + (size_t)d * NCG * 6 * FR;
    float4v acc = (float4v){0.f, 0.f, 0.f, 0.f};
#pragma unroll
    for (int ks = 0; ks < 6; ++ks) {
      int kb = ks * 32 + l4 * 4;
      Frag8 af, bfr;
      af.u[0] = *(const uint2*)&A_sm[l15][kb];
      af.u[1] = *(const uint2*)&A_sm[l15][kb + 16];
      bfr.q = *(const uint4*)(wpd + (size_t)ks * FR);
      acc = __builtin_amdgcn_mfma_f32_16x16x32_bf16(af.v, bfr.v, acc, 0, 0, 0);
    }
    float bb = bias_sm[d][ocol];
    outacc[0] += emb_sm[erow + 0][d] * (acc[0] + bb);
    outacc[1] += emb_sm[erow + 1][d] * (acc[1] + bb);
    outacc[2] += emb_sm[erow + 2][d] * (acc[2] + bb);
    outacc[3] += emb_sm[erow + 3][d] * (acc[3] + bb);
  }

  // ================= fused epilogue =================
  const int ksn = m0 >> 5;
  const int ebase = (m0 & 16) ? 4 : 0;
  const int lanep = l4 * 16 + (ocol & 15);

  if (PHASE == 0) {
    float zss[4];
#pragma unroll
    for (int r = 0; r < 4; ++r) {
      size_t m = (size_t)b * NN + m0 + erow + r;
      float zv = 1.f / (1.f + __expf(-outacc[r]));
      zr[m * 64 + ocol] = zv;
      if (ocol < 32) {
        float sv = zv * xb2[m * 32 + ocol];
        zs[m * 32 + ocol] = sv;
        zss[r] = sv;
      }
    }
    if (ocol < 32) {   // zs fragments for upd prop (2 groups/batch)
      ushort4 pk; pk.x = bf(zss[0]); pk.y = bf(zss[1]);
      pk.z = bf(zss[2]); pk.w = bf(zss[3]);
      *(ushort4*)(xbTFout + (((size_t)b * 2 + (ocol >> 4)) * 32 + ksn) * FR +
                  (size_t)lanep * 8 + ebase) = pk;
    }
  } else if (w < 2) {
    float res[4];
#pragma unroll
    for (int r = 0; r < 4; ++r) {
      size_t m = (size_t)b * NN + m0 + erow + r;
      float hc = tanhf(outacc[r]);
      float rg = zr[m * 64 + 32 + ocol];
      float st = state[m * 32 + ocol];
      res[r] = rg * st + (1.f - rg) * hc;
      hid[m * 32 + ocol] = res[r];
      if (outp) outp[m * 32 + ocol] = res[r];
    }
    if (xbTFout) {     // next gate's cur fragments (groups 0,1 of 4/batch)
      ushort4 pk; pk.x = bf(res[0]); pk.y = bf(res[1]);
      pk.z = bf(res[2]); pk.w = bf(res[3]);
      *(ushort4*)(xbTFout + (((size_t)b * 4 + (ocol >> 4)) * 32 + ksn) * FR +
                  (size_t)lanep * 8 + ebase) = pk;
    }
  }
}

// ---------------------------------------------------------------------------
extern "C" void kernel_launch(void* const* d_in, const int* in_sizes, int n_in,
                              void* d_out, int out_size, void* d_ws, size_t ws_size,
                              hipStream_t stream)
{
  const float* xt         = (const float*)d_in[0];
  const float* init_state = (const float*)d_in[1];
  const float* S          = (const float*)d_in[2];
  const float* emb        = (const float*)d_in[3];

  float* out    = (float*)d_out;          // [BN,32] final cur
  float* hidden = out + (size_t)BN * HH;  // [2, BN, 32]

  float* zr   = (float*)d_ws;                       // [BN,64]  2.0 MB
  float* zs   = zr + (size_t)BN * 64;               // [BN,32]  1.0 MB
  float* gT2c = zs + (size_t)BN * 32;               // [BN,32]  1.0 MB
  ushort* gT1c = (ushort*)(gT2c + (size_t)BN * 32); // [BN,32]  0.5 MB
  ushort* Sb   = gT1c + (size_t)BN * 32;            // row-major 2 MB
  ushort* SbF  = Sb + (size_t)NN * NN;              // frags 2 MB
  ushort* S2bF = SbF + (size_t)NN * NN;             // frags 2 MB
  ushort* wfg0 = S2bF + (size_t)NN * NN;            // 16*4*6*512  384 KB
  ushort* wfu0 = wfg0 + (size_t)DD * 4 * 6 * FR;    // 192 KB
  ushort* wfg1 = wfu0 + (size_t)DD * 2 * 6 * FR;
  ushort* wfu1 = wfg1 + (size_t)DD * 4 * 6 * FR;
  ushort* xbTFg0 = wfu1 + (size_t)DD * 2 * 6 * FR;  // 8*4*32*512  1 MB
  ushort* xbTFu0 = xbTFg0 + (size_t)BB * 4 * 32 * FR;  // 0.5 MB
  ushort* xbTFg1 = xbTFu0 + (size_t)BB * 2 * 32 * FR;  // 1 MB
  ushort* xbTFu1 = xbTFg1 + (size_t)BB * 4 * 32 * FR;  // 0.5 MB

  const float* st0 = init_state;
  const float* st1 = init_state + (size_t)BN * HH;
  float* hid0 = hidden;
  float* hid1 = hidden + (size_t)BN * HH;

  prep_all<<<1536, 256, 0, stream>>>(
      S, Sb, SbF,
      (const float*)d_in[4], (const float*)d_in[8], wfg0, wfg1,
      (const float*)d_in[6], (const float*)d_in[10], wfu0, wfu1,
      xt, st0, st1, xbTFg0, xbTFg1);
  prep_s2<<<dim3(NN / 32, NN / 32), 256, 0, stream>>>(Sb, S2bF);

  dim3 g(NN / MT, BB);   // 64 x 8 = 512 blocks
  // ---- layer 0
  gconv_fused<0><<<g, 256, 0, stream>>>(
      xt, st0, xbTFg0, SbF, S2bF, emb, wfg0, (const float*)d_in[5],
      gT1c, gT2c, zr, zs, nullptr, nullptr, nullptr, xbTFu0);
  gconv_fused<1><<<g, 256, 0, stream>>>(
      xt, zs, xbTFu0, SbF, S2bF, emb, wfu0, (const float*)d_in[7],
      gT1c, gT2c, zr, nullptr, st0, hid0, nullptr, xbTFg1);
  // ---- layer 1
  gconv_fused<0><<<g, 256, 0, stream>>>(
      hid0, st1, xbTFg1, SbF, S2bF, emb, wfg1, (const float*)d_in[9],
      gT1c, gT2c, zr, zs, nullptr, nullptr, nullptr, xbTFu1);
  gconv_fused<1><<<g, 256, 0, stream>>>(
      hid0, zs, xbTFu1, SbF, S2bF, emb, wfu1, (const float*)d_in[11],
      gT1c, gT2c, zr, nullptr, st1, hid1, out, nullptr);
}

// Round 24
// 99.870 us; speedup vs baseline: 3.7174x; 1.0045x over previous
//
#include <hip/hip_runtime.h>
#include <math.h>

#define BB 8
#define NN 1024
#define HH 32
#define II 192   // K * C = 3*64
#define DD 16
#define BN (BB*NN)
#define MT 16    // row tile
#define FR 512   // ushorts per (ks) fragment slab = 64 lanes * 8

typedef __attribute__((ext_vector_type(8))) short short8v;   // 8 bf16
typedef __attribute__((ext_vector_type(4))) float float4v;   // MFMA C/D

union Frag8 { short8v v; uint2 u[2]; uint4 q; };

// fp32 -> bf16 round-to-nearest-even (finite inputs)
static __device__ inline ushort bf(float x) {
  union { float f; unsigned u; } c; c.f = x;
  unsigned r = c.u + 0x7FFFu + ((c.u >> 16) & 1u);
  return (ushort)(r >> 16);
}

static __device__ inline uint4 pack8(const ushort e[8]) {
  uint4 v;
  v.x = (unsigned)e[0] | ((unsigned)e[1] << 16);
  v.y = (unsigned)e[2] | ((unsigned)e[3] << 16);
  v.z = (unsigned)e[4] | ((unsigned)e[5] << 16);
  v.w = (unsigned)e[6] | ((unsigned)e[7] << 16);
  return v;
}

// ---------------------------------------------------------------------------
// W[d][i][o] f32 -> fragment order WF[d][cg][ks][lane][8]
// ---------------------------------------------------------------------------
template <int O>
static __device__ void prep_w_frag(const float* __restrict__ W,
                                   ushort* __restrict__ WF, int d,
                                   float* lds)  // stride O+1
{
  constexpr int NCG = O / 16;
  const float* Wd = W + (size_t)d * II * O;
  ushort* WFd = WF + (size_t)d * NCG * 6 * FR;
  const int tid = threadIdx.x;
  for (int f = tid; f < II * O / 4; f += 256) {
    int i = f / (O / 4);
    int o4 = (f % (O / 4)) * 4;
    float4 v = *(const float4*)(Wd + (size_t)i * O + o4);
    lds[i * (O + 1) + o4 + 0] = v.x; lds[i * (O + 1) + o4 + 1] = v.y;
    lds[i * (O + 1) + o4 + 2] = v.z; lds[i * (O + 1) + o4 + 3] = v.w;
  }
  __syncthreads();
  for (int f = tid; f < NCG * 6 * 64; f += 256) {
    int rem = f % 384;
    int ks = rem >> 6, l = rem & 63;
    int o = (f / 384) * 16 + (l & 15);
    int kb = ks * 32 + (l >> 4) * 4;
    ushort e[8];
#pragma unroll
    for (int j = 0; j < 4; ++j) {
      e[j] = bf(lds[(kb + j) * (O + 1) + o]);
      e[4 + j] = bf(lds[(kb + 16 + j) * (O + 1) + o]);
    }
    *(uint4*)(WFd + (size_t)f * 8) = pack8(e);
  }
}

// ---------------------------------------------------------------------------
// prep_all (merged): [0,1024) S2bF tiles (reads f32 S directly) |
//   [1024,1056) gate W frag | [1056,1088) upd W frag |
//   [1088,1472) X transposes -> xbTF frags | [1472,1536) SbF fragments
// ---------------------------------------------------------------------------
__global__ __launch_bounds__(256) void prep_all(
    const float* __restrict__ S,
    ushort* __restrict__ SbF, ushort* __restrict__ S2bF,
    const float* __restrict__ gw0, const float* __restrict__ gw1,
    ushort* __restrict__ wfg0, ushort* __restrict__ wfg1,
    const float* __restrict__ uw0, const float* __restrict__ uw1,
    ushort* __restrict__ wfu0, ushort* __restrict__ wfu1,
    const float* __restrict__ xt, const float* __restrict__ st0,
    const float* __restrict__ st1,
    ushort* __restrict__ xbTFg0, ushort* __restrict__ xbTFg1)
{
  union PrepSm {
    float wlds[II * 65];                                    // 49.9 KB
    struct { ushort A[32][136]; ushort Bt[32][132]; ushort C2[32][36]; } s2;
    ushort T[32 * 72];
  };
  __shared__ PrepSm sm;
  int bx = blockIdx.x;
  const int tid = threadIdx.x;

  if (bx < 1024) {               // ---- S2bF tile: bf16(2*bf(S)@bf(S)) frags
    const int m0 = (bx >> 5) * 32, n0 = (bx & 31) * 32;
    const int w = tid >> 6, l = tid & 63;
    const int l15 = l & 15, l4 = l >> 4;
    const int wr = (w & 1) * 16, wc = (w >> 1) * 16;

    float4v acc = (float4v){0.f, 0.f, 0.f, 0.f};
    for (int k0 = 0; k0 < NN; k0 += 128) {
      __syncthreads();
#pragma unroll
      for (int q = 0; q < 2; ++q) {      // A rows: 32 x 128 from f32 S
        int f = tid + q * 256;
        int row = f >> 4, s8 = (f & 15) * 8;
        float4 lo = *(const float4*)(S + (size_t)(m0 + row) * NN + k0 + s8);
        float4 hi = *(const float4*)(S + (size_t)(m0 + row) * NN + k0 + s8 + 4);
        sm.s2.A[row][s8 + 0] = bf(lo.x); sm.s2.A[row][s8 + 1] = bf(lo.y);
        sm.s2.A[row][s8 + 2] = bf(lo.z); sm.s2.A[row][s8 + 3] = bf(lo.w);
        sm.s2.A[row][s8 + 4] = bf(hi.x); sm.s2.A[row][s8 + 5] = bf(hi.y);
        sm.s2.A[row][s8 + 6] = bf(hi.z); sm.s2.A[row][s8 + 7] = bf(hi.w);
      }
#pragma unroll
      for (int q = 0; q < 2; ++q) {      // B^T: S[k][n0+c] -> Bt[c][k]
        int u = tid + q * 256;
        int kp = u >> 3, c4 = (u & 7) * 4;
        float4 a = *(const float4*)(S + (size_t)(k0 + 2 * kp) * NN + n0 + c4);
        float4 b = *(const float4*)(S + (size_t)(k0 + 2 * kp + 1) * NN + n0 + c4);
        *(unsigned*)&sm.s2.Bt[c4 + 0][2 * kp] = (unsigned)bf(a.x) | ((unsigned)bf(b.x) << 16);
        *(unsigned*)&sm.s2.Bt[c4 + 1][2 * kp] = (unsigned)bf(a.y) | ((unsigned)bf(b.y) << 16);
        *(unsigned*)&sm.s2.Bt[c4 + 2][2 * kp] = (unsigned)bf(a.z) | ((unsigned)bf(b.z) << 16);
        *(unsigned*)&sm.s2.Bt[c4 + 3][2 * kp] = (unsigned)bf(a.w) | ((unsigned)bf(b.w) << 16);
      }
      __syncthreads();
#pragma unroll
      for (int ks = 0; ks < 4; ++ks) {
        int kb = ks * 32 + l4 * 4;
        Frag8 af, bfr;
        af.u[0] = *(const uint2*)&sm.s2.A[wr + l15][kb];
        af.u[1] = *(const uint2*)&sm.s2.A[wr + l15][kb + 16];
        bfr.u[0] = *(const uint2*)&sm.s2.Bt[wc + l15][kb];
        bfr.u[1] = *(const uint2*)&sm.s2.Bt[wc + l15][kb + 16];
        acc = __builtin_amdgcn_mfma_f32_16x16x32_bf16(af.v, bfr.v, acc, 0, 0, 0);
      }
    }
    __syncthreads();
#pragma unroll
    for (int r = 0; r < 4; ++r)
      sm.s2.C2[wr + l4 * 4 + r][wc + l15] = bf(2.f * acc[r]);
    __syncthreads();
    if (tid < 128) {
      int fh = tid >> 6, l2 = tid & 63;
      ushort e[8];
#pragma unroll
      for (int j = 0; j < 4; ++j) {
        e[j] = sm.s2.C2[fh * 16 + (l2 & 15)][(l2 >> 4) * 4 + j];
        e[4 + j] = sm.s2.C2[fh * 16 + (l2 & 15)][(l2 >> 4) * 4 + 16 + j];
      }
      *(uint4*)(S2bF + ((size_t)((bx >> 5) * 2 + fh) * 32 + (bx & 31)) * FR +
                (size_t)l2 * 8) = pack8(e);
    }
    return;
  }
  bx -= 1024;
  if (bx < 32) {                 // ---- gate weights -> fragments
    prep_w_frag<64>(bx >= 16 ? gw1 : gw0, bx >= 16 ? wfg1 : wfg0, bx & 15,
                    sm.wlds);
    return;
  }
  bx -= 32;
  if (bx < 32) {                 // ---- upd weights -> fragments
    prep_w_frag<32>(bx >= 16 ? uw1 : uw0, bx >= 16 ? wfu1 : wfu0, bx & 15,
                    sm.wlds);
    return;
  }
  bx -= 32;
  if (bx < 384) {                // ---- X transposes -> xbTF fragments
    const int tensor = bx / 128, seg = bx % 128;
    const float* src = tensor == 0 ? xt : (tensor == 1 ? st0 : st1);
    ushort* T = sm.T;            // [32][72]
    const int n0 = seg * 64;
#pragma unroll
    for (int q = 0; q < 2; ++q) {
      int f = tid + q * 256;
      int n = f >> 3, c4 = (f & 7) * 4;
      float4 v = *(const float4*)(src + (size_t)(n0 + n) * 32 + c4);
      T[(c4 + 0) * 72 + n] = bf(v.x); T[(c4 + 1) * 72 + n] = bf(v.y);
      T[(c4 + 2) * 72 + n] = bf(v.z); T[(c4 + 3) * 72 + n] = bf(v.w);
    }
    __syncthreads();
    {
      int gg = tid >> 7, ksl = (tid >> 6) & 1, l = tid & 63;
      int c = gg * 16 + (l & 15);
      int nb = ksl * 32 + (l >> 4) * 4;
      ushort e[8];
#pragma unroll
      for (int j = 0; j < 4; ++j) {
        e[j] = T[c * 72 + nb + j];
        e[4 + j] = T[c * 72 + nb + 16 + j];
      }
      int b = seg >> 4;                       // batch
      int ks = (seg & 15) * 2 + ksl;          // ks within batch (0..31)
      ushort* dst; int g;
      if (tensor == 0)      { dst = xbTFg0; g = gg; }      // xt -> g0 grp 0,1
      else if (tensor == 1) { dst = xbTFg0; g = 2 + gg; }  // st0 -> g0 grp 2,3
      else                  { dst = xbTFg1; g = 2 + gg; }  // st1 -> g1 grp 2,3
      *(uint4*)(dst + (((size_t)b * 4 + g) * 32 + ks) * FR + (size_t)l * 8) =
          pack8(e);
    }
    return;
  }
  bx -= 384;
  {                              // ---- SbF fragments: mt = bx (0..63)
    const int mt = bx;
#pragma unroll
    for (int q = 0; q < 8; ++q) {
      int f = tid + q * 256;     // over 32 ks * 64 lanes
      int ks = f >> 6, l = f & 63;
      int row = mt * 16 + (l & 15);
      int kb = ks * 32 + (l >> 4) * 4;
      float4 lo = *(const float4*)(S + (size_t)row * NN + kb);
      float4 hi = *(const float4*)(S + (size_t)row * NN + kb + 16);
      ushort e[8] = {bf(lo.x), bf(lo.y), bf(lo.z), bf(lo.w),
                     bf(hi.x), bf(hi.y), bf(hi.z), bf(hi.w)};
      *(uint4*)(SbF + ((size_t)mt * 32 + ks) * FR + (size_t)l * 8) = pack8(e);
    }
  }
}

// ---------------------------------------------------------------------------
// Fused graph-conv: barrier-free fragment streaming, XCD-aware block swizzle.
// Flat grid 512: bid -> mt=(bid&7)*8+((bid>>3)&7), b=bid>>6 (bijective), so
// each XCD's 64 blocks cover 8 contiguous row-tiles -> SbF/S2bF slab L2-fits.
// ---------------------------------------------------------------------------
template <int PHASE>
__global__ __launch_bounds__(256) void gconv_fused(
    const float* __restrict__ xb1,    // [BN,32] f32 (cur)
    const float* __restrict__ xb2,    // [BN,32] f32 (gate: state; upd: zs)
    const ushort* __restrict__ xbTF,  // X^T fragments (gate 4 grp; upd 2 grp)
    const ushort* __restrict__ SbF,   // S fragments
    const ushort* __restrict__ S2bF,  // 2S^2 fragments
    const float* __restrict__ emb,    // [BN,16]
    const ushort* __restrict__ WF,    // W fragments [d][cg][ks][lane][8]
    const float* __restrict__ bias,   // [16][O]
    ushort* __restrict__ gT1c,        // [BN,32] bf16: cur-half T1
    float* __restrict__ gT2c,         // [BN,32] f32 : cur-half raw T2
    float* __restrict__ zr,           // PHASE0: out [BN,64]; PHASE1: in
    float* __restrict__ zs,           // PHASE0: out [BN,32] f32
    const float* __restrict__ state,  // PHASE1: [BN,32]
    float* __restrict__ hid,          // PHASE1: out [BN,32]
    float* __restrict__ outp,         // PHASE1: dup out (may be null)
    ushort* __restrict__ xbTFout)     // PHASE0: upd frags; PHASE1: next gate
{
  constexpr int O = PHASE == 0 ? 64 : 32;
  constexpr int NCG = O / 16;         // = groups per batch in xbTF buffer
  __shared__ ushort A_sm[MT][200];    // [X | T1 | T2] bf16
  __shared__ float emb_sm[MT][17];
  __shared__ float bias_sm[16][64];

  const int bid = blockIdx.x;
  const int mt = (bid & 7) * 8 + ((bid >> 3) & 7);   // XCD-contiguous rows
  const int b = bid >> 6;
  const int m0 = mt * MT;
  const int tid = threadIdx.x;
  const int w = tid >> 6, l = tid & 63;
  const int l15 = l & 15, l4 = l >> 4;
  const int wcp = (PHASE == 0) ? w * 16 : (w & 1) * 16;

  // ---- stage emb/bias/A_sm-X early
  if (tid < MT * 4) {
    int row = tid >> 2, d4 = (tid & 3) * 4;
    float4 v = *(const float4*)(emb + ((size_t)b * NN + m0 + row) * DD + d4);
    emb_sm[row][d4 + 0] = v.x; emb_sm[row][d4 + 1] = v.y;
    emb_sm[row][d4 + 2] = v.z; emb_sm[row][d4 + 3] = v.w;
  }
  for (int f = tid; f < DD * O / 4; f += 256) {
    int d = f / (O / 4), o4 = (f % (O / 4)) * 4;
    *(float4*)&bias_sm[d][o4] = *(const float4*)(bias + (size_t)d * O + o4);
  }
  {
    int row = tid >> 4, c4 = (tid & 15) * 4;
    const float* src = (c4 < 32) ? xb1 : xb2;
    float4 v = *(const float4*)(src + ((size_t)b * NN + m0 + row) * 32 + (c4 & 31));
    ushort4 o; o.x = bf(v.x); o.y = bf(v.y); o.z = bf(v.z); o.w = bf(v.w);
    *(ushort4*)&A_sm[row][c4] = o;
  }

  // ================= phase A: propagation (fragment streams) ==============
  float4v acc1 = (float4v){0.f, 0.f, 0.f, 0.f};
  float4v acc2 = (float4v){0.f, 0.f, 0.f, 0.f};
  {
    const ushort* a1p = SbF + (size_t)mt * 32 * FR + (size_t)l * 8;
    const ushort* a2p = S2bF + (size_t)mt * 32 * FR + (size_t)l * 8;
    const ushort* bp = xbTF +
        (((size_t)b * NCG + (PHASE == 0 ? w : (w & 1))) * 32) * FR +
        (size_t)l * 8;
#pragma unroll 4
    for (int ks = 0; ks < 32; ++ks) {
      Frag8 a1, a2, b0;
      a1.q = *(const uint4*)(a1p + (size_t)ks * FR);
      a2.q = *(const uint4*)(a2p + (size_t)ks * FR);
      b0.q = *(const uint4*)(bp + (size_t)ks * FR);
      acc1 = __builtin_amdgcn_mfma_f32_16x16x32_bf16(a1.v, b0.v, acc1, 0, 0, 0);
      acc2 = __builtin_amdgcn_mfma_f32_16x16x32_bf16(a2.v, b0.v, acc2, 0, 0, 0);
    }
  }

  // ---- gate: store cur-half T1/T2 for the upd kernel (waves 0,1)
  if (PHASE == 0 && w < 2) {
#pragma unroll
    for (int r = 0; r < 4; ++r) {
      size_t m = (size_t)b * NN + m0 + l4 * 4 + r;
      gT1c[m * 32 + wcp + l15] = bf(acc1[r]);
      gT2c[m * 32 + wcp + l15] = acc2[r];
    }
  }

  // ---- finish A_sm: T1/T2 columns
  if (PHASE == 1) {   // cur-half from the gate's stores (bit-identical)
#pragma unroll
    for (int q = 0; q < 2; ++q) {
      int e = tid + q * 256;
      int row = e >> 5, c = e & 31;
      size_t m = (size_t)b * NN + m0 + row;
      A_sm[row][64 + c] = gT1c[m * 32 + c];
      A_sm[row][128 + c] = bf(gT2c[m * 32 + c] - xb1[m * 32 + c]);
    }
  }
  {
    const int colX = (PHASE == 0 ? 0 : 32) + wcp + l15;
    if (PHASE == 0 || w < 2) {
#pragma unroll
      for (int r = 0; r < 4; ++r) {
        int row = l4 * 4 + r;
        const float* src = (colX < 32) ? xb1 : xb2;
        float xv = src[((size_t)b * NN + m0 + row) * 32 + (colX & 31)];
        A_sm[row][64 + colX] = bf(acc1[r]);
        A_sm[row][128 + colX] = bf(acc2[r] - xv);
      }
    }
  }
  __syncthreads();   // the ONLY barrier

  // ================= phase B: contraction (W fragment streams) ============
  const int cg = (PHASE == 0) ? w : (w & 1);
  const int ocol = cg * 16 + l15;
  const int erow = l4 * 4;
  const ushort* wfp = WF + (size_t)cg * 6 * FR + (size_t)l * 8;

  float4v outacc = (float4v){0.f, 0.f, 0.f, 0.f};

#pragma unroll 2
  for (int d = 0; d < DD; ++d) {
    const ushort* wpd = wfp + (size_t)d * NCG * 6 * FR;
    float4v acc = (float4v){0.f, 0.f, 0.f, 0.f};
#pragma unroll
    for (int ks = 0; ks < 6; ++ks) {
      int kb = ks * 32 + l4 * 4;
      Frag8 af, bfr;
      af.u[0] = *(const uint2*)&A_sm[l15][kb];
      af.u[1] = *(const uint2*)&A_sm[l15][kb + 16];
      bfr.q = *(const uint4*)(wpd + (size_t)ks * FR);
      acc = __builtin_amdgcn_mfma_f32_16x16x32_bf16(af.v, bfr.v, acc, 0, 0, 0);
    }
    float bb = bias_sm[d][ocol];
    outacc[0] += emb_sm[erow + 0][d] * (acc[0] + bb);
    outacc[1] += emb_sm[erow + 1][d] * (acc[1] + bb);
    outacc[2] += emb_sm[erow + 2][d] * (acc[2] + bb);
    outacc[3] += emb_sm[erow + 3][d] * (acc[3] + bb);
  }

  // ================= fused epilogue =================
  const int ksn = m0 >> 5;
  const int ebase = (m0 & 16) ? 4 : 0;
  const int lanep = l4 * 16 + (ocol & 15);

  if (PHASE == 0) {
    float zss[4];
#pragma unroll
    for (int r = 0; r < 4; ++r) {
      size_t m = (size_t)b * NN + m0 + erow + r;
      float zv = 1.f / (1.f + __expf(-outacc[r]));
      zr[m * 64 + ocol] = zv;
      if (ocol < 32) {
        float sv = zv * xb2[m * 32 + ocol];
        zs[m * 32 + ocol] = sv;
        zss[r] = sv;
      }
    }
    if (ocol < 32) {   // zs fragments for upd prop (2 groups/batch)
      ushort4 pk; pk.x = bf(zss[0]); pk.y = bf(zss[1]);
      pk.z = bf(zss[2]); pk.w = bf(zss[3]);
      *(ushort4*)(xbTFout + (((size_t)b * 2 + (ocol >> 4)) * 32 + ksn) * FR +
                  (size_t)lanep * 8 + ebase) = pk;
    }
  } else if (w < 2) {
    float res[4];
#pragma unroll
    for (int r = 0; r < 4; ++r) {
      size_t m = (size_t)b * NN + m0 + erow + r;
      float hc = tanhf(outacc[r]);
      float rg = zr[m * 64 + 32 + ocol];
      float st = state[m * 32 + ocol];
      res[r] = rg * st + (1.f - rg) * hc;
      hid[m * 32 + ocol] = res[r];
      if (outp) outp[m * 32 + ocol] = res[r];
    }
    if (xbTFout) {     // next gate's cur fragments (groups 0,1 of 4/batch)
      ushort4 pk; pk.x = bf(res[0]); pk.y = bf(res[1]);
      pk.z = bf(res[2]); pk.w = bf(res[3]);
      *(ushort4*)(xbTFout + (((size_t)b * 4 + (ocol >> 4)) * 32 + ksn) * FR +
                  (size_t)lanep * 8 + ebase) = pk;
    }
  }
}

// ---------------------------------------------------------------------------
extern "C" void kernel_launch(void* const* d_in, const int* in_sizes, int n_in,
                              void* d_out, int out_size, void* d_ws, size_t ws_size,
                              hipStream_t stream)
{
  const float* xt         = (const float*)d_in[0];
  const float* init_state = (const float*)d_in[1];
  const float* S          = (const float*)d_in[2];
  const float* emb        = (const float*)d_in[3];

  float* out    = (float*)d_out;          // [BN,32] final cur
  float* hidden = out + (size_t)BN * HH;  // [2, BN, 32]

  float* zr   = (float*)d_ws;                       // [BN,64]  2.0 MB
  float* zs   = zr + (size_t)BN * 64;               // [BN,32]  1.0 MB
  float* gT2c = zs + (size_t)BN * 32;               // [BN,32]  1.0 MB
  ushort* gT1c = (ushort*)(gT2c + (size_t)BN * 32); // [BN,32]  0.5 MB
  ushort* SbF  = gT1c + (size_t)BN * 32;            // frags 2 MB
  ushort* S2bF = SbF + (size_t)NN * NN;             // frags 2 MB
  ushort* wfg0 = S2bF + (size_t)NN * NN;            // 16*4*6*512  384 KB
  ushort* wfu0 = wfg0 + (size_t)DD * 4 * 6 * FR;    // 192 KB
  ushort* wfg1 = wfu0 + (size_t)DD * 2 * 6 * FR;
  ushort* wfu1 = wfg1 + (size_t)DD * 4 * 6 * FR;
  ushort* xbTFg0 = wfu1 + (size_t)DD * 2 * 6 * FR;  // 8*4*32*512  1 MB
  ushort* xbTFu0 = xbTFg0 + (size_t)BB * 4 * 32 * FR;  // 0.5 MB
  ushort* xbTFg1 = xbTFu0 + (size_t)BB * 2 * 32 * FR;  // 1 MB
  ushort* xbTFu1 = xbTFg1 + (size_t)BB * 4 * 32 * FR;  // 0.5 MB

  const float* st0 = init_state;
  const float* st1 = init_state + (size_t)BN * HH;
  float* hid0 = hidden;
  float* hid1 = hidden + (size_t)BN * HH;

  prep_all<<<1536, 256, 0, stream>>>(
      S, SbF, S2bF,
      (const float*)d_in[4], (const float*)d_in[8], wfg0, wfg1,
      (const float*)d_in[6], (const float*)d_in[10], wfu0, wfu1,
      xt, st0, st1, xbTFg0, xbTFg1);

  // ---- layer 0
  gconv_fused<0><<<512, 256, 0, stream>>>(
      xt, st0, xbTFg0, SbF, S2bF, emb, wfg0, (const float*)d_in[5],
      gT1c, gT2c, zr, zs, nullptr, nullptr, nullptr, xbTFu0);
  gconv_fused<1><<<512, 256, 0, stream>>>(
      xt, zs, xbTFu0, SbF, S2bF, emb, wfu0, (const float*)d_in[7],
      gT1c, gT2c, zr, nullptr, st0, hid0, nullptr, xbTFg1);
  // ---- layer 1
  gconv_fused<0><<<512, 256, 0, stream>>>(
      hid0, st1, xbTFg1, SbF, S2bF, emb, wfg1, (const float*)d_in[9],
      gT1c, gT2c, zr, zs, nullptr, nullptr, nullptr, xbTFu1);
  gconv_fused<1><<<512, 256, 0, stream>>>(
      hid0, zs, xbTFu1, SbF, S2bF, emb, wfu1, (const float*)d_in[11],
      gT1c, gT2c, zr, nullptr, st1, hid1, out, nullptr);
}

// Round 25
// 94.868 us; speedup vs baseline: 3.9134x; 1.0527x over previous
//
#include <hip/hip_runtime.h>
#include <math.h>

#define BB 8
#define NN 1024
#define HH 32
#define II 192   // K * C = 3*64
#define DD 16
#define BN (BB*NN)
#define MT 16    // row tile
#define FR 512   // ushorts per (ks) fragment slab = 64 lanes * 8

typedef __attribute__((ext_vector_type(8))) short short8v;   // 8 bf16
typedef __attribute__((ext_vector_type(4))) float float4v;   // MFMA C/D

union Frag8 { short8v v; uint2 u[2]; uint4 q; };

// fp32 -> bf16 round-to-nearest-even (finite inputs)
static __device__ inline ushort bf(float x) {
  union { float f; unsigned u; } c; c.f = x;
  unsigned r = c.u + 0x7FFFu + ((c.u >> 16) & 1u);
  return (ushort)(r >> 16);
}

static __device__ inline uint4 pack8(const ushort e[8]) {
  uint4 v;
  v.x = (unsigned)e[0] | ((unsigned)e[1] << 16);
  v.y = (unsigned)e[2] | ((unsigned)e[3] << 16);
  v.z = (unsigned)e[4] | ((unsigned)e[5] << 16);
  v.w = (unsigned)e[6] | ((unsigned)e[7] << 16);
  return v;
}

// ---------------------------------------------------------------------------
// W[d][i][o] f32 -> fragment order WF[d][cg][ks][lane][8]
// ---------------------------------------------------------------------------
template <int O>
static __device__ void prep_w_frag(const float* __restrict__ W,
                                   ushort* __restrict__ WF, int d,
                                   float* lds)  // stride O+1
{
  constexpr int NCG = O / 16;
  const float* Wd = W + (size_t)d * II * O;
  ushort* WFd = WF + (size_t)d * NCG * 6 * FR;
  const int tid = threadIdx.x;
  for (int f = tid; f < II * O / 4; f += 256) {
    int i = f / (O / 4);
    int o4 = (f % (O / 4)) * 4;
    float4 v = *(const float4*)(Wd + (size_t)i * O + o4);
    lds[i * (O + 1) + o4 + 0] = v.x; lds[i * (O + 1) + o4 + 1] = v.y;
    lds[i * (O + 1) + o4 + 2] = v.z; lds[i * (O + 1) + o4 + 3] = v.w;
  }
  __syncthreads();
  for (int f = tid; f < NCG * 6 * 64; f += 256) {
    int rem = f % 384;
    int ks = rem >> 6, l = rem & 63;
    int o = (f / 384) * 16 + (l & 15);
    int kb = ks * 32 + (l >> 4) * 4;
    ushort e[8];
#pragma unroll
    for (int j = 0; j < 4; ++j) {
      e[j] = bf(lds[(kb + j) * (O + 1) + o]);
      e[4 + j] = bf(lds[(kb + 16 + j) * (O + 1) + o]);
    }
    *(uint4*)(WFd + (size_t)f * 8) = pack8(e);
  }
}

// ---------------------------------------------------------------------------
// prep_all (merged): [0,1024) S2bF tiles (reads f32 S directly) |
//   [1024,1056) gate W frag | [1056,1088) upd W frag |
//   [1088,1472) X transposes -> xbTF frags | [1472,1536) SbF fragments
// ---------------------------------------------------------------------------
__global__ __launch_bounds__(256) void prep_all(
    const float* __restrict__ S,
    ushort* __restrict__ SbF, ushort* __restrict__ S2bF,
    const float* __restrict__ gw0, const float* __restrict__ gw1,
    ushort* __restrict__ wfg0, ushort* __restrict__ wfg1,
    const float* __restrict__ uw0, const float* __restrict__ uw1,
    ushort* __restrict__ wfu0, ushort* __restrict__ wfu1,
    const float* __restrict__ xt, const float* __restrict__ st0,
    const float* __restrict__ st1,
    ushort* __restrict__ xbTFg0, ushort* __restrict__ xbTFg1)
{
  union PrepSm {
    float wlds[II * 65];                                    // 49.9 KB
    struct { ushort A[32][136]; ushort Bt[32][132]; ushort C2[32][36]; } s2;
    ushort T[32 * 72];
  };
  __shared__ PrepSm sm;
  int bx = blockIdx.x;
  const int tid = threadIdx.x;

  if (bx < 1024) {               // ---- S2bF tile: bf16(2*bf(S)@bf(S)) frags
    const int m0 = (bx >> 5) * 32, n0 = (bx & 31) * 32;
    const int w = tid >> 6, l = tid & 63;
    const int l15 = l & 15, l4 = l >> 4;
    const int wr = (w & 1) * 16, wc = (w >> 1) * 16;

    float4v acc = (float4v){0.f, 0.f, 0.f, 0.f};
    for (int k0 = 0; k0 < NN; k0 += 128) {
      __syncthreads();
#pragma unroll
      for (int q = 0; q < 2; ++q) {      // A rows: 32 x 128 from f32 S
        int f = tid + q * 256;
        int row = f >> 4, s8 = (f & 15) * 8;
        float4 lo = *(const float4*)(S + (size_t)(m0 + row) * NN + k0 + s8);
        float4 hi = *(const float4*)(S + (size_t)(m0 + row) * NN + k0 + s8 + 4);
        sm.s2.A[row][s8 + 0] = bf(lo.x); sm.s2.A[row][s8 + 1] = bf(lo.y);
        sm.s2.A[row][s8 + 2] = bf(lo.z); sm.s2.A[row][s8 + 3] = bf(lo.w);
        sm.s2.A[row][s8 + 4] = bf(hi.x); sm.s2.A[row][s8 + 5] = bf(hi.y);
        sm.s2.A[row][s8 + 6] = bf(hi.z); sm.s2.A[row][s8 + 7] = bf(hi.w);
      }
#pragma unroll
      for (int q = 0; q < 2; ++q) {      // B^T: S[k][n0+c] -> Bt[c][k]
        int u = tid + q * 256;
        int kp = u >> 3, c4 = (u & 7) * 4;
        float4 a = *(const float4*)(S + (size_t)(k0 + 2 * kp) * NN + n0 + c4);
        float4 b = *(const float4*)(S + (size_t)(k0 + 2 * kp + 1) * NN + n0 + c4);
        *(unsigned*)&sm.s2.Bt[c4 + 0][2 * kp] = (unsigned)bf(a.x) | ((unsigned)bf(b.x) << 16);
        *(unsigned*)&sm.s2.Bt[c4 + 1][2 * kp] = (unsigned)bf(a.y) | ((unsigned)bf(b.y) << 16);
        *(unsigned*)&sm.s2.Bt[c4 + 2][2 * kp] = (unsigned)bf(a.z) | ((unsigned)bf(b.z) << 16);
        *(unsigned*)&sm.s2.Bt[c4 + 3][2 * kp] = (unsigned)bf(a.w) | ((unsigned)bf(b.w) << 16);
      }
      __syncthreads();
#pragma unroll
      for (int ks = 0; ks < 4; ++ks) {
        int kb = ks * 32 + l4 * 4;
        Frag8 af, bfr;
        af.u[0] = *(const uint2*)&sm.s2.A[wr + l15][kb];
        af.u[1] = *(const uint2*)&sm.s2.A[wr + l15][kb + 16];
        bfr.u[0] = *(const uint2*)&sm.s2.Bt[wc + l15][kb];
        bfr.u[1] = *(const uint2*)&sm.s2.Bt[wc + l15][kb + 16];
        acc = __builtin_amdgcn_mfma_f32_16x16x32_bf16(af.v, bfr.v, acc, 0, 0, 0);
      }
    }
    __syncthreads();
#pragma unroll
    for (int r = 0; r < 4; ++r)
      sm.s2.C2[wr + l4 * 4 + r][wc + l15] = bf(2.f * acc[r]);
    __syncthreads();
    if (tid < 128) {
      int fh = tid >> 6, l2 = tid & 63;
      ushort e[8];
#pragma unroll
      for (int j = 0; j < 4; ++j) {
        e[j] = sm.s2.C2[fh * 16 + (l2 & 15)][(l2 >> 4) * 4 + j];
        e[4 + j] = sm.s2.C2[fh * 16 + (l2 & 15)][(l2 >> 4) * 4 + 16 + j];
      }
      *(uint4*)(S2bF + ((size_t)((bx >> 5) * 2 + fh) * 32 + (bx & 31)) * FR +
                (size_t)l2 * 8) = pack8(e);
    }
    return;
  }
  bx -= 1024;
  if (bx < 32) {                 // ---- gate weights -> fragments
    prep_w_frag<64>(bx >= 16 ? gw1 : gw0, bx >= 16 ? wfg1 : wfg0, bx & 15,
                    sm.wlds);
    return;
  }
  bx -= 32;
  if (bx < 32) {                 // ---- upd weights -> fragments
    prep_w_frag<32>(bx >= 16 ? uw1 : uw0, bx >= 16 ? wfu1 : wfu0, bx & 15,
                    sm.wlds);
    return;
  }
  bx -= 32;
  if (bx < 384) {                // ---- X transposes -> xbTF fragments
    const int tensor = bx / 128, seg = bx % 128;
    const float* src = tensor == 0 ? xt : (tensor == 1 ? st0 : st1);
    ushort* T = sm.T;            // [32][72]
    const int n0 = seg * 64;
#pragma unroll
    for (int q = 0; q < 2; ++q) {
      int f = tid + q * 256;
      int n = f >> 3, c4 = (f & 7) * 4;
      float4 v = *(const float4*)(src + (size_t)(n0 + n) * 32 + c4);
      T[(c4 + 0) * 72 + n] = bf(v.x); T[(c4 + 1) * 72 + n] = bf(v.y);
      T[(c4 + 2) * 72 + n] = bf(v.z); T[(c4 + 3) * 72 + n] = bf(v.w);
    }
    __syncthreads();
    {
      int gg = tid >> 7, ksl = (tid >> 6) & 1, l = tid & 63;
      int c = gg * 16 + (l & 15);
      int nb = ksl * 32 + (l >> 4) * 4;
      ushort e[8];
#pragma unroll
      for (int j = 0; j < 4; ++j) {
        e[j] = T[c * 72 + nb + j];
        e[4 + j] = T[c * 72 + nb + 16 + j];
      }
      int b = seg >> 4;                       // batch
      int ks = (seg & 15) * 2 + ksl;          // ks within batch (0..31)
      ushort* dst; int g;
      if (tensor == 0)      { dst = xbTFg0; g = gg; }      // xt -> g0 grp 0,1
      else if (tensor == 1) { dst = xbTFg0; g = 2 + gg; }  // st0 -> g0 grp 2,3
      else                  { dst = xbTFg1; g = 2 + gg; }  // st1 -> g1 grp 2,3
      *(uint4*)(dst + (((size_t)b * 4 + g) * 32 + ks) * FR + (size_t)l * 8) =
          pack8(e);
    }
    return;
  }
  bx -= 384;
  {                              // ---- SbF fragments: mt = bx (0..63)
    const int mt = bx;
#pragma unroll
    for (int q = 0; q < 8; ++q) {
      int f = tid + q * 256;     // over 32 ks * 64 lanes
      int ks = f >> 6, l = f & 63;
      int row = mt * 16 + (l & 15);
      int kb = ks * 32 + (l >> 4) * 4;
      float4 lo = *(const float4*)(S + (size_t)row * NN + kb);
      float4 hi = *(const float4*)(S + (size_t)row * NN + kb + 16);
      ushort e[8] = {bf(lo.x), bf(lo.y), bf(lo.z), bf(lo.w),
                     bf(hi.x), bf(hi.y), bf(hi.z), bf(hi.w)};
      *(uint4*)(SbF + ((size_t)mt * 32 + ks) * FR + (size_t)l * 8) = pack8(e);
    }
  }
}

// ---------------------------------------------------------------------------
// Fused graph-conv: fragment streaming + k-split 8-wave blocks (512 thr).
// Wave (cw,kh): cw = column group, kh = k/d half. Pair (cw,0)+(cw,1) reduce
// via LDS. 16 waves/CU = 4/SIMD (2x R24's TLP). 3 barriers total.
// ---------------------------------------------------------------------------
template <int PHASE>
__global__ __launch_bounds__(512) void gconv_fused(
    const float* __restrict__ xb1,    // [BN,32] f32 (cur)
    const float* __restrict__ xb2,    // [BN,32] f32 (gate: state; upd: zs)
    const ushort* __restrict__ xbTF,  // X^T fragments (gate 4 grp; upd 2 grp)
    const ushort* __restrict__ SbF,   // S fragments
    const ushort* __restrict__ S2bF,  // 2S^2 fragments
    const float* __restrict__ emb,    // [BN,16]
    const ushort* __restrict__ WF,    // W fragments [d][cg][ks][lane][8]
    const float* __restrict__ bias,   // [16][O]
    ushort* __restrict__ gT1c,        // [BN,32] bf16: cur-half T1
    float* __restrict__ gT2c,         // [BN,32] f32 : cur-half raw T2
    float* __restrict__ zr,           // PHASE0: out [BN,64]; PHASE1: in
    float* __restrict__ zs,           // PHASE0: out [BN,32] f32
    const float* __restrict__ state,  // PHASE1: [BN,32]
    float* __restrict__ hid,          // PHASE1: out [BN,32]
    float* __restrict__ outp,         // PHASE1: dup out (may be null)
    ushort* __restrict__ xbTFout)     // PHASE0: upd frags; PHASE1: next gate
{
  constexpr int O = PHASE == 0 ? 64 : 32;
  constexpr int NCG = O / 16;         // = groups per batch in xbTF buffer
  __shared__ ushort A_sm[MT][200];    // [X | T1 | T2] bf16
  __shared__ float emb_sm[MT][17];
  __shared__ float bias_sm[16][64];
  __shared__ float red_sm[4][64][9];  // k/d-half reduction (pad 9: 2-way max)

  const int bid = blockIdx.x;
  const int mt = (bid & 7) * 8 + ((bid >> 3) & 7);   // XCD-contiguous rows
  const int b = bid >> 6;
  const int m0 = mt * MT;
  const int tid = threadIdx.x;
  const int w = tid >> 6, l = tid & 63;
  const int cw = w & 3, kh = w >> 2;
  const int l15 = l & 15, l4 = l >> 4;
  const int wcp = (PHASE == 0) ? cw * 16 : (cw & 1) * 16;

  // ---- stage emb/bias/A_sm-X early (independent of prop)
  if (tid < MT * 4) {
    int row = tid >> 2, d4 = (tid & 3) * 4;
    float4 v = *(const float4*)(emb + ((size_t)b * NN + m0 + row) * DD + d4);
    emb_sm[row][d4 + 0] = v.x; emb_sm[row][d4 + 1] = v.y;
    emb_sm[row][d4 + 2] = v.z; emb_sm[row][d4 + 3] = v.w;
  }
  for (int f = tid; f < DD * O / 4; f += 512) {
    int d = f / (O / 4), o4 = (f % (O / 4)) * 4;
    *(float4*)&bias_sm[d][o4] = *(const float4*)(bias + (size_t)d * O + o4);
  }
  if (tid < 256) {   // X cols of A_sm: 16 rows x 64 cols = 256 float4
    int row = tid >> 4, c4 = (tid & 15) * 4;
    const float* src = (c4 < 32) ? xb1 : xb2;
    float4 v = *(const float4*)(src + ((size_t)b * NN + m0 + row) * 32 + (c4 & 31));
    ushort4 o; o.x = bf(v.x); o.y = bf(v.y); o.z = bf(v.z); o.w = bf(v.w);
    *(ushort4*)&A_sm[row][c4] = o;
  }
  if (PHASE == 1) {  // cur-half T1/T2 from gate stores: 16 rows x 32 cols
    int row = tid >> 5, c = tid & 31;
    size_t m = (size_t)b * NN + m0 + row;
    A_sm[row][64 + c] = gT1c[m * 32 + c];
    A_sm[row][128 + c] = bf(gT2c[m * 32 + c] - xb1[m * 32 + c]);
  }

  // ================= phase A: propagation, k-half kh ==============
  float4v acc1 = (float4v){0.f, 0.f, 0.f, 0.f};
  float4v acc2 = (float4v){0.f, 0.f, 0.f, 0.f};
  {
    const ushort* a1p = SbF + (size_t)mt * 32 * FR + (size_t)l * 8;
    const ushort* a2p = S2bF + (size_t)mt * 32 * FR + (size_t)l * 8;
    const ushort* bp = xbTF +
        (((size_t)b * NCG + (PHASE == 0 ? cw : (cw & 1))) * 32) * FR +
        (size_t)l * 8;
#pragma unroll 4
    for (int ks = kh * 16; ks < kh * 16 + 16; ++ks) {
      Frag8 a1, a2, b0;
      a1.q = *(const uint4*)(a1p + (size_t)ks * FR);
      a2.q = *(const uint4*)(a2p + (size_t)ks * FR);
      b0.q = *(const uint4*)(bp + (size_t)ks * FR);
      acc1 = __builtin_amdgcn_mfma_f32_16x16x32_bf16(a1.v, b0.v, acc1, 0, 0, 0);
      acc2 = __builtin_amdgcn_mfma_f32_16x16x32_bf16(a2.v, b0.v, acc2, 0, 0, 0);
    }
  }

  // ---- reduce k-halves: (cw,1) -> (cw,0)
  if (kh == 1) {
#pragma unroll
    for (int j = 0; j < 4; ++j) {
      red_sm[cw][l][j] = acc1[j];
      red_sm[cw][l][4 + j] = acc2[j];
    }
  }
  __syncthreads();   // barrier 1: red published (also covers staging)
  if (kh == 0) {
#pragma unroll
    for (int j = 0; j < 4; ++j) {
      acc1[j] += red_sm[cw][l][j];
      acc2[j] += red_sm[cw][l][4 + j];
    }
    // gate: store cur-half T1/T2 for the upd kernel (cw 0,1)
    if (PHASE == 0 && cw < 2) {
#pragma unroll
      for (int r = 0; r < 4; ++r) {
        size_t m = (size_t)b * NN + m0 + l4 * 4 + r;
        gT1c[m * 32 + wcp + l15] = bf(acc1[r]);
        gT2c[m * 32 + wcp + l15] = acc2[r];
      }
    }
    // locally-computed T1/T2 -> A_sm: gate cols 0..63; upd zs cols 32..63
    if (PHASE == 0 || cw < 2) {
      const int colX = (PHASE == 0 ? 0 : 32) + wcp + l15;
#pragma unroll
      for (int r = 0; r < 4; ++r) {
        int row = l4 * 4 + r;
        const float* src = (colX < 32) ? xb1 : xb2;
        float xv = src[((size_t)b * NN + m0 + row) * 32 + (colX & 31)];
        A_sm[row][64 + colX] = bf(acc1[r]);
        A_sm[row][128 + colX] = bf(acc2[r] - xv);
      }
    }
  }
  __syncthreads();   // barrier 2: A_sm fully published

  // ================= phase B: contraction, d-half kh ============
  const int cg = (PHASE == 0) ? cw : (cw & 1);
  const int ocol = cg * 16 + l15;
  const int erow = l4 * 4;
  const ushort* wfp = WF + (size_t)cg * 6 * FR + (size_t)l * 8;

  float4v outacc = (float4v){0.f, 0.f, 0.f, 0.f};

#pragma unroll 2
  for (int d = kh * 8; d < kh * 8 + 8; ++d) {
    const ushort* wpd = wfp + (size_t)d * NCG * 6 * FR;
    float4v acc = (float4v){0.f, 0.f, 0.f, 0.f};
#pragma unroll
    for (int ks = 0; ks < 6; ++ks) {
      int kb = ks * 32 + l4 * 4;
      Frag8 af, bfr;
      af.u[0] = *(const uint2*)&A_sm[l15][kb];
      af.u[1] = *(const uint2*)&A_sm[l15][kb + 16];
      bfr.q = *(const uint4*)(wpd + (size_t)ks * FR);
      acc = __builtin_amdgcn_mfma_f32_16x16x32_bf16(af.v, bfr.v, acc, 0, 0, 0);
    }
    float bb = bias_sm[d][ocol];
    outacc[0] += emb_sm[erow + 0][d] * (acc[0] + bb);
    outacc[1] += emb_sm[erow + 1][d] * (acc[1] + bb);
    outacc[2] += emb_sm[erow + 2][d] * (acc[2] + bb);
    outacc[3] += emb_sm[erow + 3][d] * (acc[3] + bb);
  }

  // ---- reduce d-halves: (cw,1) -> (cw,0)
  if (kh == 1) {
#pragma unroll
    for (int j = 0; j < 4; ++j) red_sm[cw][l][j] = outacc[j];
  }
  __syncthreads();   // barrier 3
  if (kh != 0) return;
#pragma unroll
  for (int j = 0; j < 4; ++j) outacc[j] += red_sm[cw][l][j];

  // ================= fused epilogue (kh==0 waves) =================
  const int ksn = m0 >> 5;
  const int ebase = (m0 & 16) ? 4 : 0;
  const int lanep = l4 * 16 + (ocol & 15);

  if (PHASE == 0) {
    float zss[4];
#pragma unroll
    for (int r = 0; r < 4; ++r) {
      size_t m = (size_t)b * NN + m0 + erow + r;
      float zv = 1.f / (1.f + __expf(-outacc[r]));
      zr[m * 64 + ocol] = zv;
      if (ocol < 32) {
        float sv = zv * xb2[m * 32 + ocol];
        zs[m * 32 + ocol] = sv;
        zss[r] = sv;
      }
    }
    if (ocol < 32) {   // zs fragments for upd prop (2 groups/batch)
      ushort4 pk; pk.x = bf(zss[0]); pk.y = bf(zss[1]);
      pk.z = bf(zss[2]); pk.w = bf(zss[3]);
      *(ushort4*)(xbTFout + (((size_t)b * 2 + (ocol >> 4)) * 32 + ksn) * FR +
                  (size_t)lanep * 8 + ebase) = pk;
    }
  } else if (cw < 2) {
    float res[4];
#pragma unroll
    for (int r = 0; r < 4; ++r) {
      size_t m = (size_t)b * NN + m0 + erow + r;
      float hc = tanhf(outacc[r]);
      float rg = zr[m * 64 + 32 + ocol];
      float st = state[m * 32 + ocol];
      res[r] = rg * st + (1.f - rg) * hc;
      hid[m * 32 + ocol] = res[r];
      if (outp) outp[m * 32 + ocol] = res[r];
    }
    if (xbTFout) {     // next gate's cur fragments (groups 0,1 of 4/batch)
      ushort4 pk; pk.x = bf(res[0]); pk.y = bf(res[1]);
      pk.z = bf(res[2]); pk.w = bf(res[3]);
      *(ushort4*)(xbTFout + (((size_t)b * 4 + (ocol >> 4)) * 32 + ksn) * FR +
                  (size_t)lanep * 8 + ebase) = pk;
    }
  }
}

// ---------------------------------------------------------------------------
extern "C" void kernel_launch(void* const* d_in, const int* in_sizes, int n_in,
                              void* d_out, int out_size, void* d_ws, size_t ws_size,
                              hipStream_t stream)
{
  const float* xt         = (const float*)d_in[0];
  const float* init_state = (const float*)d_in[1];
  const float* S          = (const float*)d_in[2];
  const float* emb        = (const float*)d_in[3];

  float* out    = (float*)d_out;          // [BN,32] final cur
  float* hidden = out + (size_t)BN * HH;  // [2, BN, 32]

  float* zr   = (float*)d_ws;                       // [BN,64]  2.0 MB
  float* zs   = zr + (size_t)BN * 64;               // [BN,32]  1.0 MB
  float* gT2c = zs + (size_t)BN * 32;               // [BN,32]  1.0 MB
  ushort* gT1c = (ushort*)(gT2c + (size_t)BN * 32); // [BN,32]  0.5 MB
  ushort* SbF  = gT1c + (size_t)BN * 32;            // frags 2 MB
  ushort* S2bF = SbF + (size_t)NN * NN;             // frags 2 MB
  ushort* wfg0 = S2bF + (size_t)NN * NN;            // 16*4*6*512  384 KB
  ushort* wfu0 = wfg0 + (size_t)DD * 4 * 6 * FR;    // 192 KB
  ushort* wfg1 = wfu0 + (size_t)DD * 2 * 6 * FR;
  ushort* wfu1 = wfg1 + (size_t)DD * 4 * 6 * FR;
  ushort* xbTFg0 = wfu1 + (size_t)DD * 2 * 6 * FR;  // 8*4*32*512  1 MB
  ushort* xbTFu0 = xbTFg0 + (size_t)BB * 4 * 32 * FR;  // 0.5 MB
  ushort* xbTFg1 = xbTFu0 + (size_t)BB * 2 * 32 * FR;  // 1 MB
  ushort* xbTFu1 = xbTFg1 + (size_t)BB * 4 * 32 * FR;  // 0.5 MB

  const float* st0 = init_state;
  const float* st1 = init_state + (size_t)BN * HH;
  float* hid0 = hidden;
  float* hid1 = hidden + (size_t)BN * HH;

  prep_all<<<1536, 256, 0, stream>>>(
      S, SbF, S2bF,
      (const float*)d_in[4], (const float*)d_in[8], wfg0, wfg1,
      (const float*)d_in[6], (const float*)d_in[10], wfu0, wfu1,
      xt, st0, st1, xbTFg0, xbTFg1);

  // ---- layer 0
  gconv_fused<0><<<512, 512, 0, stream>>>(
      xt, st0, xbTFg0, SbF, S2bF, emb, wfg0, (const float*)d_in[5],
      gT1c, gT2c, zr, zs, nullptr, nullptr, nullptr, xbTFu0);
  gconv_fused<1><<<512, 512, 0, stream>>>(
      xt, zs, xbTFu0, SbF, S2bF, emb, wfu0, (const float*)d_in[7],
      gT1c, gT2c, zr, nullptr, st0, hid0, nullptr, xbTFg1);
  // ---- layer 1
  gconv_fused<0><<<512, 512, 0, stream>>>(
      hid0, st1, xbTFg1, SbF, S2bF, emb, wfg1, (const float*)d_in[9],
      gT1c, gT2c, zr, zs, nullptr, nullptr, nullptr, xbTFu1);
  gconv_fused<1><<<512, 512, 0, stream>>>(
      hid0, zs, xbTFu1, SbF, S2bF, emb, wfu1, (const float*)d_in[11],
      gT1c, gT2c, zr, nullptr, st1, hid1, out, nullptr);
}

// Round 26
// 90.569 us; speedup vs baseline: 4.0992x; 1.0475x over previous
//
#include <hip/hip_runtime.h>
#include <math.h>

#define BB 8
#define NN 1024
#define HH 32
#define II 192   // K * C = 3*64
#define DD 16
#define BN (BB*NN)
#define FR 512   // ushorts per (ks) fragment slab = 64 lanes * 8

typedef __attribute__((ext_vector_type(8))) short short8v;   // 8 bf16
typedef __attribute__((ext_vector_type(4))) float float4v;   // MFMA C/D

union Frag8 { short8v v; uint2 u[2]; uint4 q; };

// fp32 -> bf16 round-to-nearest-even (finite inputs)
static __device__ inline ushort bf(float x) {
  union { float f; unsigned u; } c; c.f = x;
  unsigned r = c.u + 0x7FFFu + ((c.u >> 16) & 1u);
  return (ushort)(r >> 16);
}

static __device__ inline uint4 pack8(const ushort e[8]) {
  uint4 v;
  v.x = (unsigned)e[0] | ((unsigned)e[1] << 16);
  v.y = (unsigned)e[2] | ((unsigned)e[3] << 16);
  v.z = (unsigned)e[4] | ((unsigned)e[5] << 16);
  v.w = (unsigned)e[6] | ((unsigned)e[7] << 16);
  return v;
}

// ---------------------------------------------------------------------------
// W[d][i][o] f32 -> fragment order WF[d][cg][ks][lane][8]
// ---------------------------------------------------------------------------
template <int O>
static __device__ void prep_w_frag(const float* __restrict__ W,
                                   ushort* __restrict__ WF, int d,
                                   float* lds)  // stride O+1
{
  constexpr int NCG = O / 16;
  const float* Wd = W + (size_t)d * II * O;
  ushort* WFd = WF + (size_t)d * NCG * 6 * FR;
  const int tid = threadIdx.x;
  for (int f = tid; f < II * O / 4; f += 256) {
    int i = f / (O / 4);
    int o4 = (f % (O / 4)) * 4;
    float4 v = *(const float4*)(Wd + (size_t)i * O + o4);
    lds[i * (O + 1) + o4 + 0] = v.x; lds[i * (O + 1) + o4 + 1] = v.y;
    lds[i * (O + 1) + o4 + 2] = v.z; lds[i * (O + 1) + o4 + 3] = v.w;
  }
  __syncthreads();
  for (int f = tid; f < NCG * 6 * 64; f += 256) {
    int rem = f % 384;
    int ks = rem >> 6, l = rem & 63;
    int o = (f / 384) * 16 + (l & 15);
    int kb = ks * 32 + (l >> 4) * 4;
    ushort e[8];
#pragma unroll
    for (int j = 0; j < 4; ++j) {
      e[j] = bf(lds[(kb + j) * (O + 1) + o]);
      e[4 + j] = bf(lds[(kb + 16 + j) * (O + 1) + o]);
    }
    *(uint4*)(WFd + (size_t)f * 8) = pack8(e);
  }
}

// ---------------------------------------------------------------------------
// prep_all (merged): [0,1024) S2bF tiles | [1024,1056) gate W frag |
//   [1056,1088) upd W frag | [1088,1472) X transposes | [1472,1536) SbF
// ---------------------------------------------------------------------------
__global__ __launch_bounds__(256) void prep_all(
    const float* __restrict__ S,
    ushort* __restrict__ SbF, ushort* __restrict__ S2bF,
    const float* __restrict__ gw0, const float* __restrict__ gw1,
    ushort* __restrict__ wfg0, ushort* __restrict__ wfg1,
    const float* __restrict__ uw0, const float* __restrict__ uw1,
    ushort* __restrict__ wfu0, ushort* __restrict__ wfu1,
    const float* __restrict__ xt, const float* __restrict__ st0,
    const float* __restrict__ st1,
    ushort* __restrict__ xbTFg0, ushort* __restrict__ xbTFg1)
{
  union PrepSm {
    float wlds[II * 65];                                    // 49.9 KB
    struct { ushort A[32][136]; ushort Bt[32][132]; ushort C2[32][36]; } s2;
    ushort T[32 * 72];
  };
  __shared__ PrepSm sm;
  int bx = blockIdx.x;
  const int tid = threadIdx.x;

  if (bx < 1024) {               // ---- S2bF tile: bf16(2*bf(S)@bf(S)) frags
    const int m0 = (bx >> 5) * 32, n0 = (bx & 31) * 32;
    const int w = tid >> 6, l = tid & 63;
    const int l15 = l & 15, l4 = l >> 4;
    const int wr = (w & 1) * 16, wc = (w >> 1) * 16;

    float4v acc = (float4v){0.f, 0.f, 0.f, 0.f};
    for (int k0 = 0; k0 < NN; k0 += 128) {
      __syncthreads();
#pragma unroll
      for (int q = 0; q < 2; ++q) {      // A rows: 32 x 128 from f32 S
        int f = tid + q * 256;
        int row = f >> 4, s8 = (f & 15) * 8;
        float4 lo = *(const float4*)(S + (size_t)(m0 + row) * NN + k0 + s8);
        float4 hi = *(const float4*)(S + (size_t)(m0 + row) * NN + k0 + s8 + 4);
        sm.s2.A[row][s8 + 0] = bf(lo.x); sm.s2.A[row][s8 + 1] = bf(lo.y);
        sm.s2.A[row][s8 + 2] = bf(lo.z); sm.s2.A[row][s8 + 3] = bf(lo.w);
        sm.s2.A[row][s8 + 4] = bf(hi.x); sm.s2.A[row][s8 + 5] = bf(hi.y);
        sm.s2.A[row][s8 + 6] = bf(hi.z); sm.s2.A[row][s8 + 7] = bf(hi.w);
      }
#pragma unroll
      for (int q = 0; q < 2; ++q) {      // B^T: S[k][n0+c] -> Bt[c][k]
        int u = tid + q * 256;
        int kp = u >> 3, c4 = (u & 7) * 4;
        float4 a = *(const float4*)(S + (size_t)(k0 + 2 * kp) * NN + n0 + c4);
        float4 b = *(const float4*)(S + (size_t)(k0 + 2 * kp + 1) * NN + n0 + c4);
        *(unsigned*)&sm.s2.Bt[c4 + 0][2 * kp] = (unsigned)bf(a.x) | ((unsigned)bf(b.x) << 16);
        *(unsigned*)&sm.s2.Bt[c4 + 1][2 * kp] = (unsigned)bf(a.y) | ((unsigned)bf(b.y) << 16);
        *(unsigned*)&sm.s2.Bt[c4 + 2][2 * kp] = (unsigned)bf(a.z) | ((unsigned)bf(b.z) << 16);
        *(unsigned*)&sm.s2.Bt[c4 + 3][2 * kp] = (unsigned)bf(a.w) | ((unsigned)bf(b.w) << 16);
      }
      __syncthreads();
#pragma unroll
      for (int ks = 0; ks < 4; ++ks) {
        int kb = ks * 32 + l4 * 4;
        Frag8 af, bfr;
        af.u[0] = *(const uint2*)&sm.s2.A[wr + l15][kb];
        af.u[1] = *(const uint2*)&sm.s2.A[wr + l15][kb + 16];
        bfr.u[0] = *(const uint2*)&sm.s2.Bt[wc + l15][kb];
        bfr.u[1] = *(const uint2*)&sm.s2.Bt[wc + l15][kb + 16];
        acc = __builtin_amdgcn_mfma_f32_16x16x32_bf16(af.v, bfr.v, acc, 0, 0, 0);
      }
    }
    __syncthreads();
#pragma unroll
    for (int r = 0; r < 4; ++r)
      sm.s2.C2[wr + l4 * 4 + r][wc + l15] = bf(2.f * acc[r]);
    __syncthreads();
    if (tid < 128) {
      int fh = tid >> 6, l2 = tid & 63;
      ushort e[8];
#pragma unroll
      for (int j = 0; j < 4; ++j) {
        e[j] = sm.s2.C2[fh * 16 + (l2 & 15)][(l2 >> 4) * 4 + j];
        e[4 + j] = sm.s2.C2[fh * 16 + (l2 & 15)][(l2 >> 4) * 4 + 16 + j];
      }
      *(uint4*)(S2bF + ((size_t)((bx >> 5) * 2 + fh) * 32 + (bx & 31)) * FR +
                (size_t)l2 * 8) = pack8(e);
    }
    return;
  }
  bx -= 1024;
  if (bx < 32) {
    prep_w_frag<64>(bx >= 16 ? gw1 : gw0, bx >= 16 ? wfg1 : wfg0, bx & 15,
                    sm.wlds);
    return;
  }
  bx -= 32;
  if (bx < 32) {
    prep_w_frag<32>(bx >= 16 ? uw1 : uw0, bx >= 16 ? wfu1 : wfu0, bx & 15,
                    sm.wlds);
    return;
  }
  bx -= 32;
  if (bx < 384) {                // ---- X transposes -> xbTF fragments
    const int tensor = bx / 128, seg = bx % 128;
    const float* src = tensor == 0 ? xt : (tensor == 1 ? st0 : st1);
    ushort* T = sm.T;            // [32][72]
    const int n0 = seg * 64;
#pragma unroll
    for (int q = 0; q < 2; ++q) {
      int f = tid + q * 256;
      int n = f >> 3, c4 = (f & 7) * 4;
      float4 v = *(const float4*)(src + (size_t)(n0 + n) * 32 + c4);
      T[(c4 + 0) * 72 + n] = bf(v.x); T[(c4 + 1) * 72 + n] = bf(v.y);
      T[(c4 + 2) * 72 + n] = bf(v.z); T[(c4 + 3) * 72 + n] = bf(v.w);
    }
    __syncthreads();
    {
      int gg = tid >> 7, ksl = (tid >> 6) & 1, l = tid & 63;
      int c = gg * 16 + (l & 15);
      int nb = ksl * 32 + (l >> 4) * 4;
      ushort e[8];
#pragma unroll
      for (int j = 0; j < 4; ++j) {
        e[j] = T[c * 72 + nb + j];
        e[4 + j] = T[c * 72 + nb + 16 + j];
      }
      int b = seg >> 4;
      int ks = (seg & 15) * 2 + ksl;
      ushort* dst; int g;
      if (tensor == 0)      { dst = xbTFg0; g = gg; }
      else if (tensor == 1) { dst = xbTFg0; g = 2 + gg; }
      else                  { dst = xbTFg1; g = 2 + gg; }
      *(uint4*)(dst + (((size_t)b * 4 + g) * 32 + ks) * FR + (size_t)l * 8) =
          pack8(e);
    }
    return;
  }
  bx -= 384;
  {                              // ---- SbF fragments: mt = bx (0..63)
    const int mt = bx;
#pragma unroll
    for (int q = 0; q < 8; ++q) {
      int f = tid + q * 256;
      int ks = f >> 6, l = f & 63;
      int row = mt * 16 + (l & 15);
      int kb = ks * 32 + (l >> 4) * 4;
      float4 lo = *(const float4*)(S + (size_t)row * NN + kb);
      float4 hi = *(const float4*)(S + (size_t)row * NN + kb + 16);
      ushort e[8] = {bf(lo.x), bf(lo.y), bf(lo.z), bf(lo.w),
                     bf(hi.x), bf(hi.y), bf(hi.z), bf(hi.w)};
      *(uint4*)(SbF + ((size_t)mt * 32 + ks) * FR + (size_t)l * 8) = pack8(e);
    }
  }
}

// ---------------------------------------------------------------------------
// Fused graph-conv: fragment streaming, 32-row blocks (2 row tiles/wave) so
// each W/A fragment read feeds 2 MFMAs (halves L2 bytes). 512 thr, grid 256.
// Waves (cw,kh): prop k-half kh over both row tiles; contract d-half kh.
// ---------------------------------------------------------------------------
template <int PHASE>
__global__ __launch_bounds__(512) void gconv_fused(
    const float* __restrict__ xb1,    // [BN,32] f32 (cur)
    const float* __restrict__ xb2,    // [BN,32] f32 (gate: state; upd: zs)
    const ushort* __restrict__ xbTF,  // X^T fragments (gate 4 grp; upd 2 grp)
    const ushort* __restrict__ SbF,   // S fragments
    const ushort* __restrict__ S2bF,  // 2S^2 fragments
    const float* __restrict__ emb,    // [BN,16]
    const ushort* __restrict__ WF,    // W fragments [d][cg][ks][lane][8]
    const float* __restrict__ bias,   // [16][O]
    ushort* __restrict__ gT1c,        // [BN,32] bf16: cur-half T1
    float* __restrict__ gT2c,         // [BN,32] f32 : cur-half raw T2
    float* __restrict__ zr,           // PHASE0: out [BN,64]; PHASE1: in
    float* __restrict__ zs,           // PHASE0: out [BN,32] f32
    const float* __restrict__ state,  // PHASE1: [BN,32]
    float* __restrict__ hid,          // PHASE1: out [BN,32]
    float* __restrict__ outp,         // PHASE1: dup out (may be null)
    ushort* __restrict__ xbTFout)     // PHASE0: upd frags; PHASE1: next gate
{
  constexpr int O = PHASE == 0 ? 64 : 32;
  constexpr int NCG = O / 16;
  __shared__ ushort A_sm[32][200];    // [X | T1 | T2] bf16, 32 rows
  __shared__ float emb_sm[32][17];
  __shared__ float bias_sm[16][64];
  __shared__ float red1[4][2][64][4]; // [cw][rt][lane][4]
  __shared__ float red2[4][2][64][4];

  const int bid = blockIdx.x;
  // XCD-contiguous row-pairs: bid = b*32 + q*8 + s -> mtp = s*4+q (bijective)
  const int mtp = (bid & 7) * 4 + ((bid >> 3) & 3);
  const int b = bid >> 5;
  const int m0 = mtp * 32;
  const int tid = threadIdx.x;
  const int w = tid >> 6, l = tid & 63;
  const int cw = w & 3, kh = w >> 2;
  const int l15 = l & 15, l4 = l >> 4;
  const int wcp = (PHASE == 0) ? cw * 16 : (cw & 1) * 16;

  // ---- stage emb/bias/A_sm-X early
  if (tid < 128) {   // emb 32 rows x 16
    int row = tid >> 2, d4 = (tid & 3) * 4;
    float4 v = *(const float4*)(emb + ((size_t)b * NN + m0 + row) * DD + d4);
    emb_sm[row][d4 + 0] = v.x; emb_sm[row][d4 + 1] = v.y;
    emb_sm[row][d4 + 2] = v.z; emb_sm[row][d4 + 3] = v.w;
  }
  for (int f = tid; f < DD * O / 4; f += 512) {
    int d = f / (O / 4), o4 = (f % (O / 4)) * 4;
    *(float4*)&bias_sm[d][o4] = *(const float4*)(bias + (size_t)d * O + o4);
  }
  {   // X cols of A_sm: 32 rows x 64 cols = 512 float4 -> 1/thread
    int row = tid >> 4, c4 = (tid & 15) * 4;
    const float* src = (c4 < 32) ? xb1 : xb2;
    float4 v = *(const float4*)(src + ((size_t)b * NN + m0 + row) * 32 + (c4 & 31));
    ushort4 o; o.x = bf(v.x); o.y = bf(v.y); o.z = bf(v.z); o.w = bf(v.w);
    *(ushort4*)&A_sm[row][c4] = o;
  }
  if (PHASE == 1) {  // cur-half T1/T2 from gate stores: 32 rows x 32 cols
#pragma unroll
    for (int q = 0; q < 2; ++q) {
      int e = tid + q * 512;
      int row = e >> 5, c = e & 31;
      size_t m = (size_t)b * NN + m0 + row;
      A_sm[row][64 + c] = gT1c[m * 32 + c];
      A_sm[row][128 + c] = bf(gT2c[m * 32 + c] - xb1[m * 32 + c]);
    }
  }

  // ================= phase A: propagation, k-half kh, 2 row tiles =========
  float4v acc1[2], acc2[2];
#pragma unroll
  for (int rt = 0; rt < 2; ++rt) {
    acc1[rt] = (float4v){0.f, 0.f, 0.f, 0.f};
    acc2[rt] = (float4v){0.f, 0.f, 0.f, 0.f};
  }
  {
    const ushort* a1p0 = SbF + (size_t)(mtp * 2) * 32 * FR + (size_t)l * 8;
    const ushort* a2p0 = S2bF + (size_t)(mtp * 2) * 32 * FR + (size_t)l * 8;
    const ushort* bp = xbTF +
        (((size_t)b * NCG + (PHASE == 0 ? cw : (cw & 1))) * 32) * FR +
        (size_t)l * 8;
#pragma unroll 4
    for (int ks = kh * 16; ks < kh * 16 + 16; ++ks) {
      Frag8 a1r0, a1r1, a2r0, a2r1, b0;
      a1r0.q = *(const uint4*)(a1p0 + (size_t)ks * FR);
      a1r1.q = *(const uint4*)(a1p0 + (size_t)(32 + ks) * FR);
      a2r0.q = *(const uint4*)(a2p0 + (size_t)ks * FR);
      a2r1.q = *(const uint4*)(a2p0 + (size_t)(32 + ks) * FR);
      b0.q = *(const uint4*)(bp + (size_t)ks * FR);
      acc1[0] = __builtin_amdgcn_mfma_f32_16x16x32_bf16(a1r0.v, b0.v, acc1[0], 0, 0, 0);
      acc1[1] = __builtin_amdgcn_mfma_f32_16x16x32_bf16(a1r1.v, b0.v, acc1[1], 0, 0, 0);
      acc2[0] = __builtin_amdgcn_mfma_f32_16x16x32_bf16(a2r0.v, b0.v, acc2[0], 0, 0, 0);
      acc2[1] = __builtin_amdgcn_mfma_f32_16x16x32_bf16(a2r1.v, b0.v, acc2[1], 0, 0, 0);
    }
  }

  // ---- reduce k-halves: kh=1 -> kh=0
  if (kh == 1) {
#pragma unroll
    for (int rt = 0; rt < 2; ++rt)
#pragma unroll
      for (int j = 0; j < 4; ++j) {
        red1[cw][rt][l][j] = acc1[rt][j];
        red2[cw][rt][l][j] = acc2[rt][j];
      }
  }
  __syncthreads();   // barrier 1 (also covers staging)
  if (kh == 0) {
#pragma unroll
    for (int rt = 0; rt < 2; ++rt)
#pragma unroll
      for (int j = 0; j < 4; ++j) {
        acc1[rt][j] += red1[cw][rt][l][j];
        acc2[rt][j] += red2[cw][rt][l][j];
      }
    // gate: store cur-half T1/T2 for the upd kernel (cw 0,1)
    if (PHASE == 0 && cw < 2) {
#pragma unroll
      for (int rt = 0; rt < 2; ++rt)
#pragma unroll
        for (int r = 0; r < 4; ++r) {
          size_t m = (size_t)b * NN + m0 + rt * 16 + l4 * 4 + r;
          gT1c[m * 32 + wcp + l15] = bf(acc1[rt][r]);
          gT2c[m * 32 + wcp + l15] = acc2[rt][r];
        }
    }
    // locally-computed T1/T2 -> A_sm
    if (PHASE == 0 || cw < 2) {
      const int colX = (PHASE == 0 ? 0 : 32) + wcp + l15;
#pragma unroll
      for (int rt = 0; rt < 2; ++rt)
#pragma unroll
        for (int r = 0; r < 4; ++r) {
          int row = rt * 16 + l4 * 4 + r;
          const float* src = (colX < 32) ? xb1 : xb2;
          float xv = src[((size_t)b * NN + m0 + row) * 32 + (colX & 31)];
          A_sm[row][64 + colX] = bf(acc1[rt][r]);
          A_sm[row][128 + colX] = bf(acc2[rt][r] - xv);
        }
    }
  }
  __syncthreads();   // barrier 2: A_sm published

  // ================= phase B: contraction, d-half kh, 2 row tiles =========
  const int cg = (PHASE == 0) ? cw : (cw & 1);
  const int ocol = cg * 16 + l15;
  const int erow = l4 * 4;
  const ushort* wfp = WF + (size_t)cg * 6 * FR + (size_t)l * 8;

  float4v outacc[2];
  outacc[0] = (float4v){0.f, 0.f, 0.f, 0.f};
  outacc[1] = (float4v){0.f, 0.f, 0.f, 0.f};

#pragma unroll 2
  for (int d = kh * 8; d < kh * 8 + 8; ++d) {
    const ushort* wpd = wfp + (size_t)d * NCG * 6 * FR;
    float4v acc[2];
    acc[0] = (float4v){0.f, 0.f, 0.f, 0.f};
    acc[1] = (float4v){0.f, 0.f, 0.f, 0.f};
#pragma unroll
    for (int ks = 0; ks < 6; ++ks) {
      int kb = ks * 32 + l4 * 4;
      Frag8 af0, af1, bfr;
      af0.u[0] = *(const uint2*)&A_sm[l15][kb];
      af0.u[1] = *(const uint2*)&A_sm[l15][kb + 16];
      af1.u[0] = *(const uint2*)&A_sm[16 + l15][kb];
      af1.u[1] = *(const uint2*)&A_sm[16 + l15][kb + 16];
      bfr.q = *(const uint4*)(wpd + (size_t)ks * FR);
      acc[0] = __builtin_amdgcn_mfma_f32_16x16x32_bf16(af0.v, bfr.v, acc[0], 0, 0, 0);
      acc[1] = __builtin_amdgcn_mfma_f32_16x16x32_bf16(af1.v, bfr.v, acc[1], 0, 0, 0);
    }
    float bb = bias_sm[d][ocol];
#pragma unroll
    for (int rt = 0; rt < 2; ++rt) {
      outacc[rt][0] += emb_sm[rt * 16 + erow + 0][d] * (acc[rt][0] + bb);
      outacc[rt][1] += emb_sm[rt * 16 + erow + 1][d] * (acc[rt][1] + bb);
      outacc[rt][2] += emb_sm[rt * 16 + erow + 2][d] * (acc[rt][2] + bb);
      outacc[rt][3] += emb_sm[rt * 16 + erow + 3][d] * (acc[rt][3] + bb);
    }
  }

  // ---- reduce d-halves: kh=1 -> kh=0
  if (kh == 1) {
#pragma unroll
    for (int rt = 0; rt < 2; ++rt)
#pragma unroll
      for (int j = 0; j < 4; ++j) red1[cw][rt][l][j] = outacc[rt][j];
  }
  __syncthreads();   // barrier 3
  if (kh != 0) return;
#pragma unroll
  for (int rt = 0; rt < 2; ++rt)
#pragma unroll
    for (int j = 0; j < 4; ++j) outacc[rt][j] += red1[cw][rt][l][j];

  // ================= fused epilogue (kh==0 waves) =================
  const int ksn = mtp;                         // rows m0..m0+31 = one ks slab
  const int lanep = l4 * 16 + (ocol & 15);

  if (PHASE == 0) {
#pragma unroll
    for (int rt = 0; rt < 2; ++rt) {
      float zss[4];
#pragma unroll
      for (int r = 0; r < 4; ++r) {
        size_t m = (size_t)b * NN + m0 + rt * 16 + erow + r;
        float zv = 1.f / (1.f + __expf(-outacc[rt][r]));
        zr[m * 64 + ocol] = zv;
        if (ocol < 32) {
          float sv = zv * xb2[m * 32 + ocol];
          zs[m * 32 + ocol] = sv;
          zss[r] = sv;
        }
      }
      if (ocol < 32) {   // zs fragments for upd prop (2 groups/batch)
        ushort4 pk; pk.x = bf(zss[0]); pk.y = bf(zss[1]);
        pk.z = bf(zss[2]); pk.w = bf(zss[3]);
        *(ushort4*)(xbTFout + (((size_t)b * 2 + (ocol >> 4)) * 32 + ksn) * FR +
                    (size_t)lanep * 8 + rt * 4) = pk;
      }
    }
  } else if (cw < 2) {
#pragma unroll
    for (int rt = 0; rt < 2; ++rt) {
      float res[4];
#pragma unroll
      for (int r = 0; r < 4; ++r) {
        size_t m = (size_t)b * NN + m0 + rt * 16 + erow + r;
        float hc = tanhf(outacc[rt][r]);
        float rg = zr[m * 64 + 32 + ocol];
        float st = state[m * 32 + ocol];
        res[r] = rg * st + (1.f - rg) * hc;
        hid[m * 32 + ocol] = res[r];
        if (outp) outp[m * 32 + ocol] = res[r];
      }
      if (xbTFout) {     // next gate's cur fragments (groups 0,1 of 4/batch)
        ushort4 pk; pk.x = bf(res[0]); pk.y = bf(res[1]);
        pk.z = bf(res[2]); pk.w = bf(res[3]);
        *(ushort4*)(xbTFout + (((size_t)b * 4 + (ocol >> 4)) * 32 + ksn) * FR +
                    (size_t)lanep * 8 + rt * 4) = pk;
      }
    }
  }
}

// ---------------------------------------------------------------------------
extern "C" void kernel_launch(void* const* d_in, const int* in_sizes, int n_in,
                              void* d_out, int out_size, void* d_ws, size_t ws_size,
                              hipStream_t stream)
{
  const float* xt         = (const float*)d_in[0];
  const float* init_state = (const float*)d_in[1];
  const float* S          = (const float*)d_in[2];
  const float* emb        = (const float*)d_in[3];

  float* out    = (float*)d_out;          // [BN,32] final cur
  float* hidden = out + (size_t)BN * HH;  // [2, BN, 32]

  float* zr   = (float*)d_ws;                       // [BN,64]  2.0 MB
  float* zs   = zr + (size_t)BN * 64;               // [BN,32]  1.0 MB
  float* gT2c = zs + (size_t)BN * 32;               // [BN,32]  1.0 MB
  ushort* gT1c = (ushort*)(gT2c + (size_t)BN * 32); // [BN,32]  0.5 MB
  ushort* SbF  = gT1c + (size_t)BN * 32;            // frags 2 MB
  ushort* S2bF = SbF + (size_t)NN * NN;             // frags 2 MB
  ushort* wfg0 = S2bF + (size_t)NN * NN;            // 384 KB
  ushort* wfu0 = wfg0 + (size_t)DD * 4 * 6 * FR;    // 192 KB
  ushort* wfg1 = wfu0 + (size_t)DD * 2 * 6 * FR;
  ushort* wfu1 = wfg1 + (size_t)DD * 4 * 6 * FR;
  ushort* xbTFg0 = wfu1 + (size_t)DD * 2 * 6 * FR;  // 1 MB
  ushort* xbTFu0 = xbTFg0 + (size_t)BB * 4 * 32 * FR;  // 0.5 MB
  ushort* xbTFg1 = xbTFu0 + (size_t)BB * 2 * 32 * FR;  // 1 MB
  ushort* xbTFu1 = xbTFg1 + (size_t)BB * 4 * 32 * FR;  // 0.5 MB

  const float* st0 = init_state;
  const float* st1 = init_state + (size_t)BN * HH;
  float* hid0 = hidden;
  float* hid1 = hidden + (size_t)BN * HH;

  prep_all<<<1536, 256, 0, stream>>>(
      S, SbF, S2bF,
      (const float*)d_in[4], (const float*)d_in[8], wfg0, wfg1,
      (const float*)d_in[6], (const float*)d_in[10], wfu0, wfu1,
      xt, st0, st1, xbTFg0, xbTFg1);

  // ---- layer 0
  gconv_fused<0><<<256, 512, 0, stream>>>(
      xt, st0, xbTFg0, SbF, S2bF, emb, wfg0, (const float*)d_in[5],
      gT1c, gT2c, zr, zs, nullptr, nullptr, nullptr, xbTFu0);
  gconv_fused<1><<<256, 512, 0, stream>>>(
      xt, zs, xbTFu0, SbF, S2bF, emb, wfu0, (const float*)d_in[7],
      gT1c, gT2c, zr, nullptr, st0, hid0, nullptr, xbTFg1);
  // ---- layer 1
  gconv_fused<0><<<256, 512, 0, stream>>>(
      hid0, st1, xbTFg1, SbF, S2bF, emb, wfg1, (const float*)d_in[9],
      gT1c, gT2c, zr, zs, nullptr, nullptr, nullptr, xbTFu1);
  gconv_fused<1><<<256, 512, 0, stream>>>(
      hid0, zs, xbTFu1, SbF, S2bF, emb, wfu1, (const float*)d_in[11],
      gT1c, gT2c, zr, nullptr, st1, hid1, out, nullptr);
}